// Round 1
// baseline (112175.000 us; speedup 1.0000x reference)
//
#include <hip/hip_runtime.h>
#include <math.h>

#define BLK 256
static constexpr float MU_F  = 0.1f;   // MU
static constexpr float THR_F = 0.01f;  // MU*LMBD

// ---------------- block reduction (block size BLK) ----------------
__device__ inline float blk_reduce(float v) {
    __shared__ float sh[BLK];
    int tid = threadIdx.x;
    sh[tid] = v;
    __syncthreads();
    #pragma unroll
    for (int s = BLK / 2; s > 0; s >>= 1) {
        if (tid < s) sh[tid] += sh[tid + s];
        __syncthreads();
    }
    float r = sh[0];
    __syncthreads();
    return r;
}

// ---------------- per-atom weight normalization ----------------
__global__ __launch_bounds__(BLK) void wnorm_kernel(const float* __restrict__ W,
                                                    float* __restrict__ Wn, int asz) {
    int atom = blockIdx.x;
    const float* w = W + (size_t)atom * asz;
    float* o = Wn + (size_t)atom * asz;
    float s = 0.f;
    for (int i = threadIdx.x; i < asz; i += BLK) { float v = w[i]; s = fmaf(v, v, s); }
    float tot = blk_reduce(s);
    float inv = 1.0f / (sqrtf(tot) + 1e-12f);
    for (int i = threadIdx.x; i < asz; i += BLK) o[i] = w[i] * inv;
}

// ---------------- forward conv (NCHW, OIHW), fused shrink epilogue ----------------
// mode 0: out = relu(MU*acc - THR)             (z0 step)
// mode 1: out = relu(y[idx] + MU*acc - THR)    (gradient step)
template <int K>
__global__ __launch_bounds__(BLK) void conv_fwd_kernel(
    const float* __restrict__ x, const float* __restrict__ W,
    const float* __restrict__ yin, float* __restrict__ out,
    int N, int Cin, int Hin, int Win,
    int Cout, int Hout, int Wout,
    int S, int P, int mode)
{
    int idx = blockIdx.x * BLK + threadIdx.x;
    int total = N * Cout * Hout * Wout;
    if (idx >= total) return;
    int wo = idx % Wout; int t = idx / Wout;
    int ho = t % Hout; t /= Hout;
    int co = t % Cout; int n = t / Cout;

    const int h0 = ho * S - P;
    const int w0 = wo * S - P;
    const float* wb = W + (size_t)co * Cin * K * K;
    const float* xb = x + (size_t)n * Cin * Hin * Win;
    float acc = 0.f;
    for (int ci = 0; ci < Cin; ++ci) {
        const float* xc = xb + (size_t)ci * Hin * Win;
        const float* wc = wb + ci * K * K;
        #pragma unroll
        for (int kh = 0; kh < K; ++kh) {
            int h = h0 + kh;
            if ((unsigned)h < (unsigned)Hin) {
                const float* xr = xc + h * Win;
                #pragma unroll
                for (int kw = 0; kw < K; ++kw) {
                    int w = w0 + kw;
                    if ((unsigned)w < (unsigned)Win)
                        acc = fmaf(xr[w], wc[kh * K + kw], acc);
                }
            }
        }
    }
    float v = (mode == 0) ? (MU_F * acc - THR_F)
                          : (yin[idx] + MU_F * acc - THR_F);
    out[idx] = fmaxf(v, 0.f);
}

// ---------------- transpose conv ----------------
// out[n][c][ho][wo] = sum_cz,kh,kw z[n][cz][(ho+P-kh)/S][(wo+P-kw)/S] * W[cz][c][kh][kw]
// mode 0: out = aux[idx] - acc   (residual r = x - W^T z)
// mode 1: out = acc
// mode 2: out = tanhf(acc)
template <int K, int S>
__global__ __launch_bounds__(BLK) void convt_kernel(
    const float* __restrict__ z, const float* __restrict__ W,
    const float* __restrict__ aux, float* __restrict__ out,
    int N, int Cz, int Hz, int Wz,
    int Cout, int Hout, int Wout,
    int P, int mode)
{
    constexpr int MT = (K + S - 1) / S;  // max valid taps per spatial dim
    int idx = blockIdx.x * BLK + threadIdx.x;
    int total = N * Cout * Hout * Wout;
    if (idx >= total) return;
    int wo = idx % Wout; int t = idx / Wout;
    int ho = t % Hout; t /= Hout;
    int c = t % Cout; int n = t / Cout;

    // valid taps: kh with (ho+P-kh) >= 0, divisible by S, quotient < Hz
    int ph = (ho + P) % S;
    int pw = (wo + P) % S;
    int  h_[MT]; bool oh_[MT]; int kh_[MT];
    int  w_[MT]; bool ow_[MT]; int kw_[MT];
    #pragma unroll
    for (int i = 0; i < MT; ++i) {
        int kh = ph + i * S;
        int hn = ho + P - kh;
        oh_[i] = (kh < K) && (hn >= 0) && ((hn / S) < Hz);
        h_[i] = hn / S;
        kh_[i] = kh;
        int kw = pw + i * S;
        int wn = wo + P - kw;
        ow_[i] = (kw < K) && (wn >= 0) && ((wn / S) < Wz);
        w_[i] = wn / S;
        kw_[i] = kw;
    }

    float acc = 0.f;
    const float* zb = z + (size_t)n * Cz * Hz * Wz;
    for (int cz = 0; cz < Cz; ++cz) {
        const float* zc = zb + (size_t)cz * Hz * Wz;
        const float* wc = W + ((size_t)cz * Cout + c) * K * K;
        #pragma unroll
        for (int i = 0; i < MT; ++i) {
            if (oh_[i]) {
                const float* zr = zc + h_[i] * Wz;
                #pragma unroll
                for (int j = 0; j < MT; ++j) {
                    if (ow_[j])
                        acc = fmaf(zr[w_[j]], wc[kh_[i] * K + kw_[j]], acc);
                }
            }
        }
    }
    float v;
    if (mode == 0)      v = aux[idx] - acc;
    else if (mode == 1) v = acc;
    else                v = tanhf(acc);
    out[idx] = v;
}

// ---------------- FISTA momentum: y = z + c*(z - z_old) ----------------
__global__ __launch_bounds__(BLK) void y_update_kernel(
    const float* __restrict__ z, const float* __restrict__ zo,
    float* __restrict__ y, int total, float c)
{
    int i = blockIdx.x * BLK + threadIdx.x;
    if (i >= total) return;
    float zv = z[i];
    y[i] = fmaf(c, zv - zo[i], zv);
}

// ---------------- BatchNorm batch stats (biased var, eps=1e-5) ----------------
__global__ __launch_bounds__(BLK) void bn_stats_kernel(
    const float* __restrict__ x, float* __restrict__ mean, float* __restrict__ rstd,
    int N, int C, int HW)
{
    int c = blockIdx.x;
    int cnt = N * HW;
    float s = 0.f, s2 = 0.f;
    for (int i = threadIdx.x; i < cnt; i += BLK) {
        int n = i / HW, hw = i - n * HW;
        float v = x[((size_t)n * C + c) * HW + hw];
        s += v; s2 = fmaf(v, v, s2);
    }
    float ts  = blk_reduce(s);
    float ts2 = blk_reduce(s2);
    if (threadIdx.x == 0) {
        float m = ts / cnt;
        float var = ts2 / cnt - m * m;
        mean[c] = m;
        rstd[c] = rsqrtf(var + 1e-5f);
    }
}

// ---------------- BN apply + activation ----------------
// act 0: leaky relu 0.2; act 1: relu
__global__ __launch_bounds__(BLK) void bn_act_kernel(
    const float* __restrict__ x, const float* __restrict__ mean,
    const float* __restrict__ rstd, float* __restrict__ out,
    int total, int C, int HW, int use_bn, int act)
{
    int i = blockIdx.x * BLK + threadIdx.x;
    if (i >= total) return;
    float v = x[i];
    if (use_bn) { int c = (i / HW) % C; v = (v - mean[c]) * rstd[c]; }
    if (act == 0) v = (v >= 0.f) ? v : 0.2f * v;
    else          v = fmaxf(v, 0.f);
    out[i] = v;
}

// ---------------- per-row L2 normalize (z: 64x128) ----------------
__global__ __launch_bounds__(128) void rownorm_kernel(
    const float* __restrict__ z, float* __restrict__ out, float* __restrict__ zvec)
{
    __shared__ float sh[128];
    int r = blockIdx.x;
    int tid = threadIdx.x;
    float v = z[r * 128 + tid];
    sh[tid] = v * v;
    __syncthreads();
    #pragma unroll
    for (int s = 64; s > 0; s >>= 1) {
        if (tid < s) sh[tid] += sh[tid + s];
        __syncthreads();
    }
    float nrm = fmaxf(sqrtf(sh[0]), 1e-12f);
    float o = v / nrm;
    out[r * 128 + tid] = o;
    zvec[r * 128 + tid] = o;
}

static inline int gdiv(int a, int b) { return (a + b - 1) / b; }

extern "C" void kernel_launch(void* const* d_in, const int* in_sizes, int n_in,
                              void* d_out, int out_size, void* d_ws, size_t ws_size,
                              hipStream_t stream)
{
    const float* x = (const float*)d_in[0];
    const float* W[6];
    for (int i = 0; i < 6; ++i) W[i] = (const float*)d_in[1 + i];
    float* ws  = (float*)d_ws;
    float* out = (float*)d_out;

    // ---- workspace layout (floats) ----
    const size_t wnSz[6] = {3072, 131072, 524288, 2097152, 8388608, 1179648};
    float* Wn[6];
    size_t off = 0;
    for (int i = 0; i < 6; ++i) { Wn[i] = ws + off; off += wnSz[i]; }
    const size_t ARENA = 9437184;  // 64*64*48*48
    float* xb = ws + off; off += ARENA;
    float* zA = ws + off; off += ARENA;
    float* zB = ws + off; off += ARENA;
    float* yb = ws + off; off += ARENA;
    float* rb = ws + off; off += ARENA;
    float* mean = ws + off; off += 1024;
    float* rstd = ws + off; off += 1024;
    float* zvec = ws + off; off += 8192;

    // ---- normalize dictionaries ----
    const int atomCnt[6] = {64, 128, 256, 512, 1024, 128};
    const int atomSz[6]  = {48, 1024, 2048, 4096, 8192, 9216};
    for (int i = 0; i < 6; ++i)
        wnorm_kernel<<<atomCnt[i], BLK, 0, stream>>>(W[i], Wn[i], atomSz[i]);

    // ---- FISTA momentum coefficients (t0=1) ----
    double td = 1.0; float cc[3];
    for (int i = 0; i < 3; ++i) {
        double tn = (1.0 + sqrt(1.0 + 4.0 * td * td)) * 0.5;
        cc[i] = (float)((td - 1.0) / tn);
        td = tn;
    }

    // ---- layer geometry (encoder) ----
    const int Cin[6]  = {3, 64, 128, 256, 512, 1024};
    const int Cout[6] = {64, 128, 256, 512, 1024, 128};
    const int Hin[6]  = {96, 48, 24, 12, 6, 3};
    const int Hout[6] = {48, 24, 12, 6, 3, 1};
    const int Ks[6]   = {4, 4, 4, 4, 4, 3};
    const int Ss[6]   = {2, 2, 2, 2, 2, 1};
    const int Ps[6]   = {1, 1, 1, 1, 1, 0};
    const int N = 64;

    const float* in = x;
    for (int L = 0; L < 6; ++L) {
        int zTot = N * Cout[L] * Hout[L] * Hout[L];
        int xTot = N * Cin[L] * Hin[L] * Hin[L];
        dim3 gz(gdiv(zTot, BLK)), gx(gdiv(xTot, BLK));

        // z0 = shrink(MU * conv(x))
        if (Ks[L] == 4)
            conv_fwd_kernel<4><<<gz, BLK, 0, stream>>>(in, Wn[L], nullptr, zA,
                N, Cin[L], Hin[L], Hin[L], Cout[L], Hout[L], Hout[L], Ss[L], Ps[L], 0);
        else
            conv_fwd_kernel<3><<<gz, BLK, 0, stream>>>(in, Wn[L], nullptr, zA,
                N, Cin[L], Hin[L], Hin[L], Cout[L], Hout[L], Hout[L], Ss[L], Ps[L], 0);

        float* z = zA; float* zo = zB;
        for (int it = 0; it < 3; ++it) {
            const float* zold = (it == 0) ? z : zo;  // first iter: c=0, y=z
            y_update_kernel<<<gz, BLK, 0, stream>>>(z, zold, yb, zTot, cc[it]);
            // r = x - convT(y)
            if (Ks[L] == 4)
                convt_kernel<4, 2><<<gx, BLK, 0, stream>>>(yb, Wn[L], in, rb,
                    N, Cout[L], Hout[L], Hout[L], Cin[L], Hin[L], Hin[L], Ps[L], 0);
            else
                convt_kernel<3, 1><<<gx, BLK, 0, stream>>>(yb, Wn[L], in, rb,
                    N, Cout[L], Hout[L], Hout[L], Cin[L], Hin[L], Hin[L], Ps[L], 0);
            // z_new = shrink(y + MU*conv(r)), into zo
            if (Ks[L] == 4)
                conv_fwd_kernel<4><<<gz, BLK, 0, stream>>>(rb, Wn[L], yb, zo,
                    N, Cin[L], Hin[L], Hin[L], Cout[L], Hout[L], Hout[L], Ss[L], Ps[L], 1);
            else
                conv_fwd_kernel<3><<<gz, BLK, 0, stream>>>(rb, Wn[L], yb, zo,
                    N, Cin[L], Hin[L], Hin[L], Cout[L], Hout[L], Hout[L], Ss[L], Ps[L], 1);
            float* tmp = z; z = zo; zo = tmp;
        }

        int HW = Hout[L] * Hout[L];
        if (L == 0) {
            bn_act_kernel<<<gz, BLK, 0, stream>>>(z, nullptr, nullptr, xb, zTot, Cout[L], HW, 0, 0);
            in = xb;
        } else if (L < 5) {
            bn_stats_kernel<<<Cout[L], BLK, 0, stream>>>(z, mean, rstd, N, Cout[L], HW);
            bn_act_kernel<<<gz, BLK, 0, stream>>>(z, mean, rstd, xb, zTot, Cout[L], HW, 1, 0);
            in = xb;
        } else {
            rownorm_kernel<<<64, 128, 0, stream>>>(z, out, zvec);
        }
    }

    // ---- decoder ----
    // h = relu(bn(convT(z, Wn6, s1 p0))): (64,128,1,1) -> (64,1024,3,3)
    {
        int oT = N * 1024 * 9;
        dim3 g(gdiv(oT, BLK));
        convt_kernel<3, 1><<<g, BLK, 0, stream>>>(zvec, Wn[5], nullptr, zA,
            N, 128, 1, 1, 1024, 3, 3, 0, 1);
        bn_stats_kernel<<<1024, BLK, 0, stream>>>(zA, mean, rstd, N, 1024, 9);
        bn_act_kernel<<<g, BLK, 0, stream>>>(zA, mean, rstd, zB, oT, 1024, 9, 1, 1);
    }
    // chain: i = 4,3,2,1 : (64,Cout[i],Hout[i],.) -> (64,Cin[i],Hin[i],.)
    float* cur = zB;
    for (int i = 4; i >= 1; --i) {
        int oT = N * Cin[i] * Hin[i] * Hin[i];
        dim3 g(gdiv(oT, BLK));
        convt_kernel<4, 2><<<g, BLK, 0, stream>>>(cur, Wn[i], nullptr, zA,
            N, Cout[i], Hout[i], Hout[i], Cin[i], Hin[i], Hin[i], 1, 1);
        bn_stats_kernel<<<Cin[i], BLK, 0, stream>>>(zA, mean, rstd, N, Cin[i], Hin[i] * Hin[i]);
        bn_act_kernel<<<g, BLK, 0, stream>>>(zA, mean, rstd, zB, oT, Cin[i], Hin[i] * Hin[i], 1, 1);
        cur = zB;
    }
    // x_hat = tanh(convT(h, Wn1, s2 p1)): (64,64,48,48) -> (64,3,96,96)
    {
        int oT = N * 3 * 96 * 96;
        dim3 g(gdiv(oT, BLK));
        convt_kernel<4, 2><<<g, BLK, 0, stream>>>(cur, Wn[0], nullptr, out + 8192,
            N, 64, 48, 48, 3, 96, 96, 1, 2);
    }
}

// Round 3
// 10389.307 us; speedup vs baseline: 10.7972x; 10.7972x over previous
//
#include <hip/hip_runtime.h>
#include <math.h>

#define BLK 256
static constexpr float MU_F  = 0.1f;
static constexpr float THR_F = 0.01f;

// ---------------- block reduction ----------------
__device__ inline float blk_reduce(float v) {
    __shared__ float sh[BLK];
    int tid = threadIdx.x;
    sh[tid] = v;
    __syncthreads();
    #pragma unroll
    for (int s = BLK / 2; s > 0; s >>= 1) {
        if (tid < s) sh[tid] += sh[tid + s];
        __syncthreads();
    }
    float r = sh[0];
    __syncthreads();
    return r;
}

// ---------------- normalize dictionary atom + pack ----------------
// W: [Mout][Cm][Kk][Kk] (OIHW), atom = o (block). asz = Cm*KK*Kk... = Cm*KKtot.
// Wkc[k][o]   = Wn[o][k]        (K-major, contiguous in o — conv fwd GEMM + convT transpose-stage)
// Wnout[o][k] = Wn[o][k]        (row-major copy, only for L5 outer_gemm)
__global__ __launch_bounds__(BLK) void wnorm_pack(
    const float* __restrict__ W, float* __restrict__ Wkc,
    float* __restrict__ Wnout, int Mout, int asz)
{
    int o = blockIdx.x;
    const float* w = W + (size_t)o * asz;
    float s = 0.f;
    for (int i = threadIdx.x; i < asz; i += BLK) { float v = w[i]; s = fmaf(v, v, s); }
    float tot = blk_reduce(s);
    float inv = 1.0f / (sqrtf(tot) + 1e-12f);
    for (int i = threadIdx.x; i < asz; i += BLK) {
        float v = w[i] * inv;
        Wkc[(size_t)i * Mout + o] = v;
        if (Wnout) Wnout[(size_t)o * asz + i] = v;
    }
}

// ---------------- implicit-GEMM forward conv ----------------
// out[m][p] = sum_k Wp[k][m] * im2col(x)[k][p], tile 64x64, BK=16.
// emode 0: relu(MU*acc-THR); 1: relu(yin[idx]+MU*acc-THR); 2: atomicAdd raw (split-K)
template <int KK, int Kk, int S, int P>
__global__ __launch_bounds__(BLK) void conv_gemm(
    const float* __restrict__ Wp, const float* __restrict__ x,
    const float* __restrict__ yin, float* __restrict__ out,
    int M, int Ktot, int Cx, int Hx, int Wx, int Hout, int Wout,
    int kchunk, int emode)
{
    __shared__ float Wt[16][64];
    __shared__ float Xt[16][64];
    int tid = threadIdx.x, tx = tid & 15, ty = tid >> 4;
    int HW = Hout * Wout, HWx = Hx * Wx;
    int pbase = blockIdx.x * 64 + tx * 4;
    int n_[4], ho_[4], wo_[4];
    const float* xb_[4];
    #pragma unroll
    for (int j = 0; j < 4; ++j) {
        int p = pbase + j; int n = p / HW; int r = p - n * HW;
        int ho = r / Wout; int wo = r - ho * Wout;
        n_[j] = n; ho_[j] = ho; wo_[j] = wo;
        xb_[j] = x + (size_t)n * Cx * HWx;
    }
    int m0 = blockIdx.y * 64;
    int kb = blockIdx.z * kchunk, ke = kb + kchunk;
    if (ke > Ktot) ke = Ktot;
    float acc[4][4] = {};
    for (int k0 = kb; k0 < ke; k0 += 16) {
        int kr = k0 + ty;
        *(float4*)&Wt[ty][tx * 4] = *(const float4*)&Wp[(size_t)kr * M + m0 + tx * 4];
        int ci = kr / KK; int t = kr - ci * KK; int kh = t / Kk; int kw = t - kh * Kk;
        int cio = ci * HWx;
        float g[4];
        #pragma unroll
        for (int j = 0; j < 4; ++j) {
            int h = ho_[j] * S - P + kh, w = wo_[j] * S - P + kw;
            g[j] = ((unsigned)h < (unsigned)Hx && (unsigned)w < (unsigned)Wx)
                 ? xb_[j][cio + h * Wx + w] : 0.f;
        }
        *(float4*)&Xt[ty][tx * 4] = make_float4(g[0], g[1], g[2], g[3]);
        __syncthreads();
        #pragma unroll
        for (int kk = 0; kk < 16; ++kk) {
            float4 a = *(float4*)&Wt[kk][ty * 4];
            float4 b = *(float4*)&Xt[kk][tx * 4];
            float aa[4] = {a.x, a.y, a.z, a.w};
            float bb[4] = {b.x, b.y, b.z, b.w};
            #pragma unroll
            for (int i = 0; i < 4; ++i)
                #pragma unroll
                for (int j = 0; j < 4; ++j)
                    acc[i][j] = fmaf(aa[i], bb[j], acc[i][j]);
        }
        __syncthreads();
    }
    #pragma unroll
    for (int i = 0; i < 4; ++i) {
        int m = m0 + ty * 4 + i;
        #pragma unroll
        for (int j = 0; j < 4; ++j) {
            size_t idx = (((size_t)n_[j] * M + m) * Hout + ho_[j]) * Wout + wo_[j];
            float v = acc[i][j];
            if (emode == 0)      out[idx] = fmaxf(MU_F * v - THR_F, 0.f);
            else if (emode == 1) out[idx] = fmaxf(yin[idx] + MU_F * v - THR_F, 0.f);
            else                 atomicAdd(&out[idx], v);
        }
    }
}

// ---------------- implicit-GEMM transpose conv (K=4,S=2,P=1), parity classes ----------------
// blockIdx.z = hbit*2+wbit (output pixel parity). K-dim = Cz*4 (2x2 taps per class).
// Weights staged from Wkc layout [(c*16+tap)][cz]: float4 along cz, transpose-write to LDS.
// emode 0: aux[idx]-acc (residual); 1: acc.  Requires M % 64 == 0.
__global__ __launch_bounds__(BLK) void convt_gemm(
    const float* __restrict__ Wp, const float* __restrict__ z,
    const float* __restrict__ aux, float* __restrict__ out,
    int M, int Cz, int Hz, int Wz, int Ho, int Wo, int emode)
{
    __shared__ float Wt[16][64];
    __shared__ float Xt[16][64];
    int tid = threadIdx.x, tx = tid & 15, ty = tid >> 4;
    int hbit = blockIdx.z >> 1, wbit = blockIdx.z & 1;
    int khp = 1 - hbit, kwp = 1 - wbit;
    int Hc = Ho >> 1, Wc = Wo >> 1, HWc = Hc * Wc;
    int pbase = blockIdx.x * 64 + tx * 4;
    int n_[4], hc_[4], wc_[4];
    #pragma unroll
    for (int j = 0; j < 4; ++j) {
        int p = pbase + j; int n = p / HWc; int r = p - n * HWc;
        n_[j] = n; hc_[j] = r / Wc; wc_[j] = r - (r / Wc) * Wc;
    }
    int m0 = blockIdx.y * 64;
    int Ktot = Cz * 4;
    // weight staging assignment: thread -> (column c_l, tap tt)
    int c_l = tid >> 2, tt = tid & 3;
    int tap = (khp + 2 * (tt >> 1)) * 4 + (kwp + 2 * (tt & 1));
    const float* wsrc = Wp + ((size_t)(m0 + c_l) * 16 + tap) * Cz;
    float acc[4][4] = {};
    for (int k0 = 0; k0 < Ktot; k0 += 16) {
        int cz0 = k0 >> 2;
        float4 wv = *(const float4*)&wsrc[cz0];
        Wt[tt     ][c_l] = wv.x;
        Wt[4  + tt][c_l] = wv.y;
        Wt[8  + tt][c_l] = wv.z;
        Wt[12 + tt][c_l] = wv.w;
        int kr = k0 + ty;
        int cz = kr >> 2, t = kr & 3, ti = t >> 1, tj = t & 1;
        float g[4];
        #pragma unroll
        for (int j = 0; j < 4; ++j) {
            int hn = hc_[j] + hbit - ti, wn = wc_[j] + wbit - tj;
            g[j] = ((unsigned)hn < (unsigned)Hz && (unsigned)wn < (unsigned)Wz)
                 ? z[(((size_t)n_[j] * Cz + cz) * Hz + hn) * Wz + wn] : 0.f;
        }
        *(float4*)&Xt[ty][tx * 4] = make_float4(g[0], g[1], g[2], g[3]);
        __syncthreads();
        #pragma unroll
        for (int kk = 0; kk < 16; ++kk) {
            float4 a = *(float4*)&Wt[kk][ty * 4];
            float4 b = *(float4*)&Xt[kk][tx * 4];
            float aa[4] = {a.x, a.y, a.z, a.w};
            float bb[4] = {b.x, b.y, b.z, b.w};
            #pragma unroll
            for (int i = 0; i < 4; ++i)
                #pragma unroll
                for (int j = 0; j < 4; ++j)
                    acc[i][j] = fmaf(aa[i], bb[j], acc[i][j]);
        }
        __syncthreads();
    }
    #pragma unroll
    for (int i = 0; i < 4; ++i) {
        int m = m0 + ty * 4 + i;
        #pragma unroll
        for (int j = 0; j < 4; ++j) {
            int ho = 2 * hc_[j] + hbit, wo = 2 * wc_[j] + wbit;
            size_t idx = (((size_t)n_[j] * M + m) * Ho + ho) * Wo + wo;
            float v = acc[i][j];
            out[idx] = (emode == 0) ? (aux[idx] - v) : v;
        }
    }
}

// ---------------- 1x1-source transpose conv as plain GEMM ----------------
// out[n][m] = sum_cz zin[n][cz] * Wp[cz][m]  (Wp = normalized OIHW, [128][9216])
// emode 0: aux - acc; 1: acc
__global__ __launch_bounds__(BLK) void outer_gemm(
    const float* __restrict__ Wp, const float* __restrict__ zin,
    const float* __restrict__ aux, float* __restrict__ out,
    int M, int Kz, int emode)
{
    __shared__ float Wt[16][64];
    __shared__ float Xt[16][64];
    int tid = threadIdx.x, tx = tid & 15, ty = tid >> 4;
    int m0 = blockIdx.y * 64;
    float acc[4][4] = {};
    for (int k0 = 0; k0 < Kz; k0 += 16) {
        int kr = k0 + ty;
        *(float4*)&Wt[ty][tx * 4] = *(const float4*)&Wp[(size_t)kr * M + m0 + tx * 4];
        float g[4];
        #pragma unroll
        for (int j = 0; j < 4; ++j) g[j] = zin[(size_t)(tx * 4 + j) * Kz + kr];
        *(float4*)&Xt[ty][tx * 4] = make_float4(g[0], g[1], g[2], g[3]);
        __syncthreads();
        #pragma unroll
        for (int kk = 0; kk < 16; ++kk) {
            float4 a = *(float4*)&Wt[kk][ty * 4];
            float4 b = *(float4*)&Xt[kk][tx * 4];
            float aa[4] = {a.x, a.y, a.z, a.w};
            float bb[4] = {b.x, b.y, b.z, b.w};
            #pragma unroll
            for (int i = 0; i < 4; ++i)
                #pragma unroll
                for (int j = 0; j < 4; ++j)
                    acc[i][j] = fmaf(aa[i], bb[j], acc[i][j]);
        }
        __syncthreads();
    }
    #pragma unroll
    for (int i = 0; i < 4; ++i) {
        int m = m0 + ty * 4 + i;
        #pragma unroll
        for (int j = 0; j < 4; ++j) {
            int n = tx * 4 + j;
            size_t idx = (size_t)n * M + m;
            float v = acc[i][j];
            out[idx] = (emode == 0) ? (aux[idx] - v) : v;
        }
    }
}

// ---------------- M=3 transpose conv (image space), weights in LDS ----------------
// Weights read from Wkc[0] layout [(c*16+tap)][64].  emode 0: aux - acc; 2: tanh(acc)
__global__ __launch_bounds__(BLK) void convt_m3(
    const float* __restrict__ Wkc0, const float* __restrict__ z,
    const float* __restrict__ aux, float* __restrict__ out,
    int Cz, int Hz, int Wz, int Ho, int Wo, int emode)
{
    __shared__ float Wl[64 * 4 * 3];
    int tid = threadIdx.x;
    int hbit = blockIdx.z >> 1, wbit = blockIdx.z & 1;
    int khp = 1 - hbit, kwp = 1 - wbit;
    int Ktot = Cz * 4;
    for (int kidx = tid; kidx < Ktot; kidx += BLK) {
        int cz = kidx >> 2, t = kidx & 3, ti = t >> 1, tj = t & 1;
        int tap = (khp + 2 * ti) * 4 + (kwp + 2 * tj);
        Wl[kidx * 3 + 0] = Wkc0[(0 * 16 + tap) * 64 + cz];
        Wl[kidx * 3 + 1] = Wkc0[(1 * 16 + tap) * 64 + cz];
        Wl[kidx * 3 + 2] = Wkc0[(2 * 16 + tap) * 64 + cz];
    }
    __syncthreads();
    int Hc = Ho >> 1, Wc = Wo >> 1, HWc = Hc * Wc;
    int p = blockIdx.x * BLK + tid;
    int n = p / HWc, r = p - n * HWc, hc = r / Wc, wc = r - (r / Wc) * Wc;
    const float* zb = z + (size_t)n * Cz * Hz * Wz;
    int offs[4]; bool val[4];
    #pragma unroll
    for (int t = 0; t < 4; ++t) {
        int ti = t >> 1, tj = t & 1;
        int hn = hc + hbit - ti, wn = wc + wbit - tj;
        val[t] = ((unsigned)hn < (unsigned)Hz) && ((unsigned)wn < (unsigned)Wz);
        offs[t] = hn * Wz + wn;
    }
    float a0 = 0.f, a1 = 0.f, a2 = 0.f;
    int HWz = Hz * Wz;
    for (int cz = 0; cz < Cz; ++cz) {
        const float* base = zb + cz * HWz;
        #pragma unroll
        for (int t = 0; t < 4; ++t) {
            float g = val[t] ? base[offs[t]] : 0.f;
            int wi = (cz * 4 + t) * 3;
            a0 = fmaf(g, Wl[wi + 0], a0);
            a1 = fmaf(g, Wl[wi + 1], a1);
            a2 = fmaf(g, Wl[wi + 2], a2);
        }
    }
    int ho = 2 * hc + hbit, wo = 2 * wc + wbit;
    #pragma unroll
    for (int u = 0; u < 3; ++u) {
        float v = (u == 0) ? a0 : (u == 1) ? a1 : a2;
        size_t idx = (((size_t)n * 3 + u) * Ho + ho) * Wo + wo;
        out[idx] = (emode == 0) ? (aux[idx] - v) : tanhf(v);
    }
}

// ---------------- small epilogue for split-K L5 conv ----------------
__global__ __launch_bounds__(BLK) void l5_epi(
    const float* __restrict__ p, const float* __restrict__ y,
    float* __restrict__ o, int n, int mode)
{
    int i = blockIdx.x * BLK + threadIdx.x;
    if (i >= n) return;
    float v = MU_F * p[i] - THR_F;
    if (mode == 1) v += y[i];
    o[i] = fmaxf(v, 0.f);
}

// ---------------- FISTA y-update ----------------
__global__ __launch_bounds__(BLK) void y_update_kernel(
    const float* __restrict__ z, const float* __restrict__ zo,
    float* __restrict__ y, int total, float c)
{
    int i = blockIdx.x * BLK + threadIdx.x;
    if (i >= total) return;
    float zv = z[i];
    y[i] = fmaf(c, zv - zo[i], zv);
}

// ---------------- BN stats ----------------
__global__ __launch_bounds__(BLK) void bn_stats_kernel(
    const float* __restrict__ x, float* __restrict__ mean, float* __restrict__ rstd,
    int N, int C, int HW)
{
    int c = blockIdx.x;
    int cnt = N * HW;
    float s = 0.f, s2 = 0.f;
    for (int i = threadIdx.x; i < cnt; i += BLK) {
        int n = i / HW, hw = i - n * HW;
        float v = x[((size_t)n * C + c) * HW + hw];
        s += v; s2 = fmaf(v, v, s2);
    }
    float ts  = blk_reduce(s);
    float ts2 = blk_reduce(s2);
    if (threadIdx.x == 0) {
        float m = ts / cnt;
        float var = ts2 / cnt - m * m;
        mean[c] = m;
        rstd[c] = rsqrtf(var + 1e-5f);
    }
}

// ---------------- BN apply + activation (act 0: lrelu 0.2, act 1: relu) ----------------
__global__ __launch_bounds__(BLK) void bn_act_kernel(
    const float* __restrict__ x, const float* __restrict__ mean,
    const float* __restrict__ rstd, float* __restrict__ out,
    int total, int C, int HW, int use_bn, int act)
{
    int i = blockIdx.x * BLK + threadIdx.x;
    if (i >= total) return;
    float v = x[i];
    if (use_bn) { int c = (i / HW) % C; v = (v - mean[c]) * rstd[c]; }
    out[i] = (act == 0) ? ((v >= 0.f) ? v : 0.2f * v) : fmaxf(v, 0.f);
}

// ---------------- per-row L2 normalize ----------------
__global__ __launch_bounds__(128) void rownorm_kernel(
    const float* __restrict__ z, float* __restrict__ out, float* __restrict__ zvec)
{
    __shared__ float sh[128];
    int r = blockIdx.x, tid = threadIdx.x;
    float v = z[r * 128 + tid];
    sh[tid] = v * v;
    __syncthreads();
    #pragma unroll
    for (int s = 64; s > 0; s >>= 1) {
        if (tid < s) sh[tid] += sh[tid + s];
        __syncthreads();
    }
    float nrm = fmaxf(sqrtf(sh[0]), 1e-12f);
    float o = v / nrm;
    out[r * 128 + tid] = o;
    zvec[r * 128 + tid] = o;
}

static inline int gdiv(int a, int b) { return (a + b - 1) / b; }

extern "C" void kernel_launch(void* const* d_in, const int* in_sizes, int n_in,
                              void* d_out, int out_size, void* d_ws, size_t ws_size,
                              hipStream_t stream)
{
    const float* x = (const float*)d_in[0];
    const float* W[6];
    for (int i = 0; i < 6; ++i) W[i] = (const float*)d_in[1 + i];
    float* ws  = (float*)d_ws;
    float* out = (float*)d_out;

    const int Cin[6]  = {3, 64, 128, 256, 512, 1024};
    const int Cout[6] = {64, 128, 256, 512, 1024, 128};
    const int Hin[6]  = {96, 48, 24, 12, 6, 3};
    const int Hout[6] = {48, 24, 12, 6, 3, 1};
    const size_t wsz[6] = {3072, 131072, 524288, 2097152, 8388608, 1179648};
    const int N = 64;

    // ---- workspace layout (floats), total ~53.0M floats = 212 MB ----
    float* Wkc[6]; float* Wn5;
    size_t off = 0;
    for (int i = 0; i < 6; ++i) { Wkc[i] = ws + off; off += wsz[i]; }
    Wn5 = ws + off; off += wsz[5];
    const size_t POOL = 30081024;   // max over layers of 3*zTot + xTot  (L0 exactly)
    float* pool = ws + off; off += POOL;
    float* xb   = ws + off; off += 9437184;   // max activation (64*64*48*48)
    float* mean = ws + off; off += 1024;
    float* rstd = ws + off; off += 1024;
    float* zvec = ws + off; off += 8192;
    float* pbuf = ws + off; off += 8192;

    // ---- normalize + pack dictionaries ----
    for (int L = 0; L < 5; ++L)
        wnorm_pack<<<Cout[L], BLK, 0, stream>>>(W[L], Wkc[L], nullptr, Cout[L], Cin[L] * 16);
    wnorm_pack<<<128, BLK, 0, stream>>>(W[5], Wkc[5], Wn5, 128, 9216);

    // ---- FISTA momentum coefficients ----
    double td = 1.0; float cc[3];
    for (int i = 0; i < 3; ++i) {
        double tn = (1.0 + sqrt(1.0 + 4.0 * td * td)) * 0.5;
        cc[i] = (float)((td - 1.0) / tn);
        td = tn;
    }

    const float* in = x;
    for (int L = 0; L < 6; ++L) {
        int zTot = N * Cout[L] * Hout[L] * Hout[L];
        int npix = N * Hout[L] * Hout[L];
        dim3 gz(npix / 64, Cout[L] / 64);
        dim3 ge(gdiv(zTot, BLK));

        // per-layer carve from pool: zA, zB, yb (zTot each) + rb (xTot)
        float* zA = pool;
        float* zB = pool + (size_t)zTot;
        float* yb = pool + (size_t)2 * zTot;
        float* rb = pool + (size_t)3 * zTot;

        // z0 = shrink(MU * conv(in))
        if (L < 5) {
            conv_gemm<16, 4, 2, 1><<<gz, BLK, 0, stream>>>(Wkc[L], in, nullptr, zA,
                Cout[L], Cin[L] * 16, Cin[L], Hin[L], Hin[L], Hout[L], Hout[L],
                Cin[L] * 16, 0);
        } else {
            hipMemsetAsync(pbuf, 0, 8192 * 4, stream);
            conv_gemm<9, 3, 1, 0><<<dim3(1, 2, 72), BLK, 0, stream>>>(Wkc[5], in, nullptr,
                pbuf, 128, 9216, 1024, 3, 3, 1, 1, 128, 2);
            l5_epi<<<32, BLK, 0, stream>>>(pbuf, nullptr, zA, 8192, 0);
        }

        float* z = zA; float* zo = zB;
        for (int it = 0; it < 3; ++it) {
            const float* zold = (it == 0) ? z : zo;
            y_update_kernel<<<ge, BLK, 0, stream>>>(z, zold, yb, zTot, cc[it]);
            // r = in - convT(y)
            if (L == 0) {
                convt_m3<<<dim3(N * 48 * 48 / BLK, 1, 4), BLK, 0, stream>>>(
                    Wkc[0], yb, in, rb, 64, 48, 48, 96, 96, 0);
            } else if (L < 5) {
                int xpixc = N * (Hin[L] / 2) * (Hin[L] / 2);
                convt_gemm<<<dim3(xpixc / 64, Cin[L] / 64, 4), BLK, 0, stream>>>(
                    Wkc[L], yb, in, rb, Cin[L], Cout[L], Hout[L], Hout[L],
                    Hin[L], Hin[L], 0);
            } else {
                outer_gemm<<<dim3(1, 144), BLK, 0, stream>>>(Wn5, yb, in, rb, 9216, 128, 0);
            }
            // z_new = shrink(y + MU*conv(r))
            if (L < 5) {
                conv_gemm<16, 4, 2, 1><<<gz, BLK, 0, stream>>>(Wkc[L], rb, yb, zo,
                    Cout[L], Cin[L] * 16, Cin[L], Hin[L], Hin[L], Hout[L], Hout[L],
                    Cin[L] * 16, 1);
            } else {
                hipMemsetAsync(pbuf, 0, 8192 * 4, stream);
                conv_gemm<9, 3, 1, 0><<<dim3(1, 2, 72), BLK, 0, stream>>>(Wkc[5], rb,
                    nullptr, pbuf, 128, 9216, 1024, 3, 3, 1, 1, 128, 2);
                l5_epi<<<32, BLK, 0, stream>>>(pbuf, yb, zo, 8192, 1);
            }
            float* tmp = z; z = zo; zo = tmp;
        }

        int HW = Hout[L] * Hout[L];
        if (L == 0) {
            bn_act_kernel<<<ge, BLK, 0, stream>>>(z, nullptr, nullptr, xb, zTot, Cout[L], HW, 0, 0);
            in = xb;
        } else if (L < 5) {
            bn_stats_kernel<<<Cout[L], BLK, 0, stream>>>(z, mean, rstd, N, Cout[L], HW);
            bn_act_kernel<<<ge, BLK, 0, stream>>>(z, mean, rstd, xb, zTot, Cout[L], HW, 1, 0);
            in = xb;
        } else {
            rownorm_kernel<<<64, 128, 0, stream>>>(z, out, zvec);
        }
    }

    // ---- decoder (zA/zB regions both fit in pool: 2 x 9437184 <= POOL) ----
    float* zA = pool;
    float* zB = pool + 9437184;
    {
        int oT = N * 1024 * 9;
        outer_gemm<<<dim3(1, 144), BLK, 0, stream>>>(Wn5, zvec, nullptr, zA, 9216, 128, 1);
        bn_stats_kernel<<<1024, BLK, 0, stream>>>(zA, mean, rstd, N, 1024, 9);
        bn_act_kernel<<<gdiv(oT, BLK), BLK, 0, stream>>>(zA, mean, rstd, zB, oT, 1024, 9, 1, 1);
    }
    float* cur = zB;
    for (int i = 4; i >= 1; --i) {
        int oT = N * Cin[i] * Hin[i] * Hin[i];
        int xpixc = N * (Hin[i] / 2) * (Hin[i] / 2);
        convt_gemm<<<dim3(xpixc / 64, Cin[i] / 64, 4), BLK, 0, stream>>>(
            Wkc[i], cur, nullptr, zA, Cin[i], Cout[i], Hout[i], Hout[i],
            Hin[i], Hin[i], 1);
        bn_stats_kernel<<<Cin[i], BLK, 0, stream>>>(zA, mean, rstd, N, Cin[i], Hin[i] * Hin[i]);
        bn_act_kernel<<<gdiv(oT, BLK), BLK, 0, stream>>>(zA, mean, rstd, zB, oT,
            Cin[i], Hin[i] * Hin[i], 1, 1);
        cur = zB;
    }
    convt_m3<<<dim3(N * 48 * 48 / BLK, 1, 4), BLK, 0, stream>>>(
        Wkc[0], cur, nullptr, out + 8192, 64, 48, 48, 96, 96, 2);
}

// Round 4
// 9033.566 us; speedup vs baseline: 12.4176x; 1.1501x over previous
//
#include <hip/hip_runtime.h>
#include <math.h>

#define BLK 256
static constexpr float MU_F  = 0.1f;
static constexpr float THR_F = 0.01f;

// ---------------- block reduction ----------------
__device__ inline float blk_reduce(float v) {
    __shared__ float sh[BLK];
    int tid = threadIdx.x;
    sh[tid] = v;
    __syncthreads();
    #pragma unroll
    for (int s = BLK / 2; s > 0; s >>= 1) {
        if (tid < s) sh[tid] += sh[tid + s];
        __syncthreads();
    }
    float r = sh[0];
    __syncthreads();
    return r;
}

// ---------------- normalize dictionary atom + pack ----------------
// Wkc[k][o]   = Wn[o][k]   (K-major, contiguous in o)
// Wnout[o][k] = Wn[o][k]   (row-major, only L5)
__global__ __launch_bounds__(BLK) void wnorm_pack(
    const float* __restrict__ W, float* __restrict__ Wkc,
    float* __restrict__ Wnout, int Mout, int asz)
{
    int o = blockIdx.x;
    const float* w = W + (size_t)o * asz;
    float s = 0.f;
    for (int i = threadIdx.x; i < asz; i += BLK) { float v = w[i]; s = fmaf(v, v, s); }
    float tot = blk_reduce(s);
    float inv = 1.0f / (sqrtf(tot) + 1e-12f);
    for (int i = threadIdx.x; i < asz; i += BLK) {
        float v = w[i] * inv;
        Wkc[(size_t)i * Mout + o] = v;
        if (Wnout) Wnout[(size_t)o * asz + i] = v;
    }
}

// ---------------- implicit-GEMM forward conv ----------------
// emode 0: relu(MU*acc-THR); 1: relu(yin[idx]+MU*acc-THR); 2: atomicAdd raw (split-K)
template <int KK, int Kk, int S, int P>
__global__ __launch_bounds__(BLK) void conv_gemm(
    const float* __restrict__ Wp, const float* __restrict__ x,
    const float* __restrict__ yin, float* __restrict__ out,
    int M, int Ktot, int Cx, int Hx, int Wx, int Hout, int Wout,
    int kchunk, int emode)
{
    __shared__ float Wt[16][64];
    __shared__ float Xt[16][64];
    int tid = threadIdx.x, tx = tid & 15, ty = tid >> 4;
    int HW = Hout * Wout, HWx = Hx * Wx;
    int pbase = blockIdx.x * 64 + tx * 4;
    int n_[4], ho_[4], wo_[4];
    const float* xb_[4];
    #pragma unroll
    for (int j = 0; j < 4; ++j) {
        int p = pbase + j; int n = p / HW; int r = p - n * HW;
        int ho = r / Wout; int wo = r - ho * Wout;
        n_[j] = n; ho_[j] = ho; wo_[j] = wo;
        xb_[j] = x + (size_t)n * Cx * HWx;
    }
    int m0 = blockIdx.y * 64;
    int kb = blockIdx.z * kchunk, ke = kb + kchunk;
    if (ke > Ktot) ke = Ktot;
    float acc[4][4] = {};
    for (int k0 = kb; k0 < ke; k0 += 16) {
        int kr = k0 + ty;
        *(float4*)&Wt[ty][tx * 4] = *(const float4*)&Wp[(size_t)kr * M + m0 + tx * 4];
        int ci = kr / KK; int t = kr - ci * KK; int kh = t / Kk; int kw = t - kh * Kk;
        int cio = ci * HWx;
        float g[4];
        #pragma unroll
        for (int j = 0; j < 4; ++j) {
            int h = ho_[j] * S - P + kh, w = wo_[j] * S - P + kw;
            g[j] = ((unsigned)h < (unsigned)Hx && (unsigned)w < (unsigned)Wx)
                 ? xb_[j][cio + h * Wx + w] : 0.f;
        }
        *(float4*)&Xt[ty][tx * 4] = make_float4(g[0], g[1], g[2], g[3]);
        __syncthreads();
        #pragma unroll
        for (int kk = 0; kk < 16; ++kk) {
            float4 a = *(float4*)&Wt[kk][ty * 4];
            float4 b = *(float4*)&Xt[kk][tx * 4];
            float aa[4] = {a.x, a.y, a.z, a.w};
            float bb[4] = {b.x, b.y, b.z, b.w};
            #pragma unroll
            for (int i = 0; i < 4; ++i)
                #pragma unroll
                for (int j = 0; j < 4; ++j)
                    acc[i][j] = fmaf(aa[i], bb[j], acc[i][j]);
        }
        __syncthreads();
    }
    #pragma unroll
    for (int i = 0; i < 4; ++i) {
        int m = m0 + ty * 4 + i;
        #pragma unroll
        for (int j = 0; j < 4; ++j) {
            size_t idx = (((size_t)n_[j] * M + m) * Hout + ho_[j]) * Wout + wo_[j];
            float v = acc[i][j];
            if (emode == 0)      out[idx] = fmaxf(MU_F * v - THR_F, 0.f);
            else if (emode == 1) out[idx] = fmaxf(yin[idx] + MU_F * v - THR_F, 0.f);
            else                 atomicAdd(&out[idx], v);
        }
    }
}

// ---------------- implicit-GEMM transpose conv (K=4,S=2,P=1) ----------------
// blockIdx.z = parity*SK + chunk. Per parity the tap set is fixed 2x2; split-K over cz.
// emode 0: aux-acc; 1: acc; 2: atomicAdd raw (split-K, out pre-zeroed)
__global__ __launch_bounds__(BLK) void convt_gemm(
    const float* __restrict__ Wp, const float* __restrict__ z,
    const float* __restrict__ aux, float* __restrict__ out,
    int M, int Cz, int Hz, int Wz, int Ho, int Wo, int emode, int SK)
{
    __shared__ float Wt[16][64];
    __shared__ float Xt[16][64];
    int tid = threadIdx.x, tx = tid & 15, ty = tid >> 4;
    int zi = blockIdx.z;
    int par = zi / SK, chunk = zi - par * SK;
    int hbit = par >> 1, wbit = par & 1;
    int khp = 1 - hbit, kwp = 1 - wbit;
    int czs = Cz / SK, cz0 = chunk * czs;
    int Hc = Ho >> 1, Wc = Wo >> 1, HWc = Hc * Wc;
    int pbase = blockIdx.x * 64 + tx * 4;
    int n_[4], hc_[4], wc_[4];
    #pragma unroll
    for (int j = 0; j < 4; ++j) {
        int p = pbase + j; int n = p / HWc; int r = p - n * HWc;
        n_[j] = n; hc_[j] = r / Wc; wc_[j] = r - (r / Wc) * Wc;
    }
    int m0 = blockIdx.y * 64;
    // weight staging: thread -> (column c_l, tap tt); float4 along cz
    int c_l = tid >> 2, tt = tid & 3;
    int tap = (khp + 2 * (tt >> 1)) * 4 + (kwp + 2 * (tt & 1));
    const float* wsrc = Wp + ((size_t)(m0 + c_l) * 16 + tap) * Cz + cz0;
    float acc[4][4] = {};
    for (int k0 = 0; k0 < czs * 4; k0 += 16) {
        float4 wv = *(const float4*)&wsrc[k0 >> 2];
        Wt[tt     ][c_l] = wv.x;
        Wt[4  + tt][c_l] = wv.y;
        Wt[8  + tt][c_l] = wv.z;
        Wt[12 + tt][c_l] = wv.w;
        int kr = k0 + ty;
        int cz = cz0 + (kr >> 2); int t = kr & 3, ti = t >> 1, tj = t & 1;
        float g[4];
        #pragma unroll
        for (int j = 0; j < 4; ++j) {
            int hn = hc_[j] + hbit - ti, wn = wc_[j] + wbit - tj;
            g[j] = ((unsigned)hn < (unsigned)Hz && (unsigned)wn < (unsigned)Wz)
                 ? z[(((size_t)n_[j] * Cz + cz) * Hz + hn) * Wz + wn] : 0.f;
        }
        *(float4*)&Xt[ty][tx * 4] = make_float4(g[0], g[1], g[2], g[3]);
        __syncthreads();
        #pragma unroll
        for (int kk = 0; kk < 16; ++kk) {
            float4 a = *(float4*)&Wt[kk][ty * 4];
            float4 b = *(float4*)&Xt[kk][tx * 4];
            float aa[4] = {a.x, a.y, a.z, a.w};
            float bb[4] = {b.x, b.y, b.z, b.w};
            #pragma unroll
            for (int i = 0; i < 4; ++i)
                #pragma unroll
                for (int j = 0; j < 4; ++j)
                    acc[i][j] = fmaf(aa[i], bb[j], acc[i][j]);
        }
        __syncthreads();
    }
    #pragma unroll
    for (int i = 0; i < 4; ++i) {
        int m = m0 + ty * 4 + i;
        #pragma unroll
        for (int j = 0; j < 4; ++j) {
            int ho = 2 * hc_[j] + hbit, wo = 2 * wc_[j] + wbit;
            size_t idx = (((size_t)n_[j] * M + m) * Ho + ho) * Wo + wo;
            float v = acc[i][j];
            if (emode == 0)      out[idx] = aux[idx] - v;
            else if (emode == 1) out[idx] = v;
            else                 atomicAdd(&out[idx], v);
        }
    }
}

// ---------------- 1x1-source transpose conv as plain GEMM ----------------
__global__ __launch_bounds__(BLK) void outer_gemm(
    const float* __restrict__ Wp, const float* __restrict__ zin,
    const float* __restrict__ aux, float* __restrict__ out,
    int M, int Kz, int emode)
{
    __shared__ float Wt[16][64];
    __shared__ float Xt[16][64];
    int tid = threadIdx.x, tx = tid & 15, ty = tid >> 4;
    int m0 = blockIdx.y * 64;
    float acc[4][4] = {};
    for (int k0 = 0; k0 < Kz; k0 += 16) {
        int kr = k0 + ty;
        *(float4*)&Wt[ty][tx * 4] = *(const float4*)&Wp[(size_t)kr * M + m0 + tx * 4];
        float g[4];
        #pragma unroll
        for (int j = 0; j < 4; ++j) g[j] = zin[(size_t)(tx * 4 + j) * Kz + kr];
        *(float4*)&Xt[ty][tx * 4] = make_float4(g[0], g[1], g[2], g[3]);
        __syncthreads();
        #pragma unroll
        for (int kk = 0; kk < 16; ++kk) {
            float4 a = *(float4*)&Wt[kk][ty * 4];
            float4 b = *(float4*)&Xt[kk][tx * 4];
            float aa[4] = {a.x, a.y, a.z, a.w};
            float bb[4] = {b.x, b.y, b.z, b.w};
            #pragma unroll
            for (int i = 0; i < 4; ++i)
                #pragma unroll
                for (int j = 0; j < 4; ++j)
                    acc[i][j] = fmaf(aa[i], bb[j], acc[i][j]);
        }
        __syncthreads();
    }
    #pragma unroll
    for (int i = 0; i < 4; ++i) {
        int m = m0 + ty * 4 + i;
        #pragma unroll
        for (int j = 0; j < 4; ++j) {
            int n = tx * 4 + j;
            size_t idx = (size_t)n * M + m;
            float v = acc[i][j];
            out[idx] = (emode == 0) ? (aux[idx] - v) : v;
        }
    }
}

// ---------------- M=3 transpose conv (image space) ----------------
__global__ __launch_bounds__(BLK) void convt_m3(
    const float* __restrict__ Wkc0, const float* __restrict__ z,
    const float* __restrict__ aux, float* __restrict__ out,
    int Cz, int Hz, int Wz, int Ho, int Wo, int emode)
{
    __shared__ float Wl[64 * 4 * 3];
    int tid = threadIdx.x;
    int hbit = blockIdx.z >> 1, wbit = blockIdx.z & 1;
    int khp = 1 - hbit, kwp = 1 - wbit;
    int Ktot = Cz * 4;
    for (int kidx = tid; kidx < Ktot; kidx += BLK) {
        int cz = kidx >> 2, t = kidx & 3, ti = t >> 1, tj = t & 1;
        int tap = (khp + 2 * ti) * 4 + (kwp + 2 * tj);
        Wl[kidx * 3 + 0] = Wkc0[(0 * 16 + tap) * 64 + cz];
        Wl[kidx * 3 + 1] = Wkc0[(1 * 16 + tap) * 64 + cz];
        Wl[kidx * 3 + 2] = Wkc0[(2 * 16 + tap) * 64 + cz];
    }
    __syncthreads();
    int Hc = Ho >> 1, Wc = Wo >> 1, HWc = Hc * Wc;
    int p = blockIdx.x * BLK + tid;
    int n = p / HWc, r = p - n * HWc, hc = r / Wc, wc = r - (r / Wc) * Wc;
    const float* zb = z + (size_t)n * Cz * Hz * Wz;
    int offs[4]; bool val[4];
    #pragma unroll
    for (int t = 0; t < 4; ++t) {
        int ti = t >> 1, tj = t & 1;
        int hn = hc + hbit - ti, wn = wc + wbit - tj;
        val[t] = ((unsigned)hn < (unsigned)Hz) && ((unsigned)wn < (unsigned)Wz);
        offs[t] = hn * Wz + wn;
    }
    float a0 = 0.f, a1 = 0.f, a2 = 0.f;
    int HWz = Hz * Wz;
    for (int cz = 0; cz < Cz; ++cz) {
        const float* base = zb + cz * HWz;
        #pragma unroll
        for (int t = 0; t < 4; ++t) {
            float g = val[t] ? base[offs[t]] : 0.f;
            int wi = (cz * 4 + t) * 3;
            a0 = fmaf(g, Wl[wi + 0], a0);
            a1 = fmaf(g, Wl[wi + 1], a1);
            a2 = fmaf(g, Wl[wi + 2], a2);
        }
    }
    int ho = 2 * hc + hbit, wo = 2 * wc + wbit;
    #pragma unroll
    for (int u = 0; u < 3; ++u) {
        float v = (u == 0) ? a0 : (u == 1) ? a1 : a2;
        size_t idx = (((size_t)n * 3 + u) * Ho + ho) * Wo + wo;
        out[idx] = (emode == 0) ? (aux[idx] - v) : tanhf(v);
    }
}

// ---------------- shrink epilogue (split-K conv): relu([y+] MU*p - THR) ----------------
__global__ __launch_bounds__(BLK) void shrink_epi(
    const float* __restrict__ p, const float* __restrict__ y,
    float* __restrict__ o, int n, int mode)
{
    int i = blockIdx.x * BLK + threadIdx.x;
    if (i >= n) return;
    float v = MU_F * p[i] - THR_F;
    if (mode == 1) v += y[i];
    o[i] = fmaxf(v, 0.f);
}

// ---------------- residual epilogue (split-K convT): o = aux - acc (in-place ok) ----------------
__global__ __launch_bounds__(BLK) void res_epi(
    const float* __restrict__ aux, const float* __restrict__ acc,
    float* __restrict__ o, int n)
{
    int i = blockIdx.x * BLK + threadIdx.x;
    if (i >= n) return;
    o[i] = aux[i] - acc[i];
}

// ---------------- FISTA y-update ----------------
__global__ __launch_bounds__(BLK) void y_update_kernel(
    const float* __restrict__ z, const float* __restrict__ zo,
    float* __restrict__ y, int total, float c)
{
    int i = blockIdx.x * BLK + threadIdx.x;
    if (i >= total) return;
    float zv = z[i];
    y[i] = fmaf(c, zv - zo[i], zv);
}

// ---------------- BN stats ----------------
__global__ __launch_bounds__(BLK) void bn_stats_kernel(
    const float* __restrict__ x, float* __restrict__ mean, float* __restrict__ rstd,
    int N, int C, int HW)
{
    int c = blockIdx.x;
    int cnt = N * HW;
    float s = 0.f, s2 = 0.f;
    for (int i = threadIdx.x; i < cnt; i += BLK) {
        int n = i / HW, hw = i - n * HW;
        float v = x[((size_t)n * C + c) * HW + hw];
        s += v; s2 = fmaf(v, v, s2);
    }
    float ts  = blk_reduce(s);
    float ts2 = blk_reduce(s2);
    if (threadIdx.x == 0) {
        float m = ts / cnt;
        float var = ts2 / cnt - m * m;
        mean[c] = m;
        rstd[c] = rsqrtf(var + 1e-5f);
    }
}

// ---------------- BN apply + activation (act 0: lrelu 0.2, act 1: relu) ----------------
__global__ __launch_bounds__(BLK) void bn_act_kernel(
    const float* __restrict__ x, const float* __restrict__ mean,
    const float* __restrict__ rstd, float* __restrict__ out,
    int total, int C, int HW, int use_bn, int act)
{
    int i = blockIdx.x * BLK + threadIdx.x;
    if (i >= total) return;
    float v = x[i];
    if (use_bn) { int c = (i / HW) % C; v = (v - mean[c]) * rstd[c]; }
    out[i] = (act == 0) ? ((v >= 0.f) ? v : 0.2f * v) : fmaxf(v, 0.f);
}

// ---------------- per-row L2 normalize ----------------
__global__ __launch_bounds__(128) void rownorm_kernel(
    const float* __restrict__ z, float* __restrict__ out, float* __restrict__ zvec)
{
    __shared__ float sh[128];
    int r = blockIdx.x, tid = threadIdx.x;
    float v = z[r * 128 + tid];
    sh[tid] = v * v;
    __syncthreads();
    #pragma unroll
    for (int s = 64; s > 0; s >>= 1) {
        if (tid < s) sh[tid] += sh[tid + s];
        __syncthreads();
    }
    float nrm = fmaxf(sqrtf(sh[0]), 1e-12f);
    float o = v / nrm;
    out[r * 128 + tid] = o;
    zvec[r * 128 + tid] = o;
}

static inline int gdiv(int a, int b) { return (a + b - 1) / b; }

extern "C" void kernel_launch(void* const* d_in, const int* in_sizes, int n_in,
                              void* d_out, int out_size, void* d_ws, size_t ws_size,
                              hipStream_t stream)
{
    const float* x = (const float*)d_in[0];
    const float* W[6];
    for (int i = 0; i < 6; ++i) W[i] = (const float*)d_in[1 + i];
    float* ws  = (float*)d_ws;
    float* out = (float*)d_out;

    const int Cin[6]  = {3, 64, 128, 256, 512, 1024};
    const int Cout[6] = {64, 128, 256, 512, 1024, 128};
    const int Hin[6]  = {96, 48, 24, 12, 6, 3};
    const int Hout[6] = {48, 24, 12, 6, 3, 1};
    const size_t wsz[6] = {3072, 131072, 524288, 2097152, 8388608, 1179648};
    const int N = 64;
    // split-K factors for conv (z-space GEMM) and convT (x-space GEMM), per layer
    const int SKc[6] = {1, 1, 2, 4, 8, 1};
    const int SKt[6] = {1, 1, 1, 2, 4, 1};

    // ---- workspace layout (floats), total ~55.4M floats = 222 MB ----
    float* Wkc[6]; float* Wn5;
    size_t off = 0;
    for (int i = 0; i < 6; ++i) { Wkc[i] = ws + off; off += wsz[i]; }
    Wn5 = ws + off; off += wsz[5];
    const size_t POOL = 30081024;   // max over layers of 3*zTot + xTot (L0 exactly)
    float* pool = ws + off; off += POOL;
    float* xb   = ws + off; off += 9437184;
    float* mean = ws + off; off += 1024;
    float* rstd = ws + off; off += 1024;
    float* zvec = ws + off; off += 8192;
    float* pbuf = ws + off; off += 2359296;   // max split-K partial (L2 zTot)

    // ---- normalize + pack dictionaries ----
    for (int L = 0; L < 5; ++L)
        wnorm_pack<<<Cout[L], BLK, 0, stream>>>(W[L], Wkc[L], nullptr, Cout[L], Cin[L] * 16);
    wnorm_pack<<<128, BLK, 0, stream>>>(W[5], Wkc[5], Wn5, 128, 9216);

    // ---- FISTA momentum coefficients ----
    double td = 1.0; float cc[3];
    for (int i = 0; i < 3; ++i) {
        double tn = (1.0 + sqrt(1.0 + 4.0 * td * td)) * 0.5;
        cc[i] = (float)((td - 1.0) / tn);
        td = tn;
    }

    const float* in = x;
    for (int L = 0; L < 6; ++L) {
        int zTot = N * Cout[L] * Hout[L] * Hout[L];
        int xTot = N * Cin[L] * Hin[L] * Hin[L];
        int npix = N * Hout[L] * Hout[L];
        dim3 ge(gdiv(zTot, BLK));
        dim3 gr(gdiv(xTot, BLK));

        float* zA = pool;
        float* zB = pool + (size_t)zTot;
        float* yb = pool + (size_t)2 * zTot;
        float* rb = pool + (size_t)3 * zTot;

        // --- helper lambdas (host-side) ---
        auto launch_conv = [&](const float* src, const float* y, float* dst, int mode) {
            // mode 0: z0 shrink; mode 1: grad shrink
            if (L == 5) {
                hipMemsetAsync(pbuf, 0, (size_t)zTot * 4, stream);
                conv_gemm<9, 3, 1, 0><<<dim3(1, 2, 72), BLK, 0, stream>>>(Wkc[5], src,
                    nullptr, pbuf, 128, 9216, 1024, 3, 3, 1, 1, 128, 2);
                shrink_epi<<<gdiv(zTot, BLK), BLK, 0, stream>>>(pbuf, y, dst, zTot, mode);
            } else if (SKc[L] == 1) {
                conv_gemm<16, 4, 2, 1><<<dim3(npix / 64, Cout[L] / 64), BLK, 0, stream>>>(
                    Wkc[L], src, y, dst, Cout[L], Cin[L] * 16, Cin[L], Hin[L], Hin[L],
                    Hout[L], Hout[L], Cin[L] * 16, mode);
            } else {
                int sk = SKc[L];
                hipMemsetAsync(pbuf, 0, (size_t)zTot * 4, stream);
                conv_gemm<16, 4, 2, 1><<<dim3(npix / 64, Cout[L] / 64, sk), BLK, 0, stream>>>(
                    Wkc[L], src, nullptr, pbuf, Cout[L], Cin[L] * 16, Cin[L], Hin[L], Hin[L],
                    Hout[L], Hout[L], Cin[L] * 16 / sk, 2);
                shrink_epi<<<gdiv(zTot, BLK), BLK, 0, stream>>>(pbuf, y, dst, zTot, mode);
            }
        };

        // z0 = shrink(MU * conv(in))
        launch_conv(in, nullptr, zA, 0);

        float* z = zA; float* zo = zB;
        for (int it = 0; it < 3; ++it) {
            const float* zold = (it == 0) ? z : zo;
            y_update_kernel<<<ge, BLK, 0, stream>>>(z, zold, yb, zTot, cc[it]);
            // r = in - convT(y)
            if (L == 0) {
                convt_m3<<<dim3(N * 48 * 48 / BLK, 1, 4), BLK, 0, stream>>>(
                    Wkc[0], yb, in, rb, 64, 48, 48, 96, 96, 0);
            } else if (L < 5) {
                int xpixc = N * (Hin[L] / 2) * (Hin[L] / 2);
                int sk = SKt[L];
                if (sk == 1) {
                    convt_gemm<<<dim3(xpixc / 64, Cin[L] / 64, 4), BLK, 0, stream>>>(
                        Wkc[L], yb, in, rb, Cin[L], Cout[L], Hout[L], Hout[L],
                        Hin[L], Hin[L], 0, 1);
                } else {
                    hipMemsetAsync(rb, 0, (size_t)xTot * 4, stream);
                    convt_gemm<<<dim3(xpixc / 64, Cin[L] / 64, 4 * sk), BLK, 0, stream>>>(
                        Wkc[L], yb, nullptr, rb, Cin[L], Cout[L], Hout[L], Hout[L],
                        Hin[L], Hin[L], 2, sk);
                    res_epi<<<gr, BLK, 0, stream>>>(in, rb, rb, xTot);
                }
            } else {
                outer_gemm<<<dim3(1, 144), BLK, 0, stream>>>(Wn5, yb, in, rb, 9216, 128, 0);
            }
            // z_new = shrink(y + MU*conv(r))
            launch_conv(rb, yb, zo, 1);
            float* tmp = z; z = zo; zo = tmp;
        }

        int HW = Hout[L] * Hout[L];
        if (L == 0) {
            bn_act_kernel<<<ge, BLK, 0, stream>>>(z, nullptr, nullptr, xb, zTot, Cout[L], HW, 0, 0);
            in = xb;
        } else if (L < 5) {
            bn_stats_kernel<<<Cout[L], BLK, 0, stream>>>(z, mean, rstd, N, Cout[L], HW);
            bn_act_kernel<<<ge, BLK, 0, stream>>>(z, mean, rstd, xb, zTot, Cout[L], HW, 1, 0);
            in = xb;
        } else {
            rownorm_kernel<<<64, 128, 0, stream>>>(z, out, zvec);
        }
    }

    // ---- decoder ----
    float* zA = pool;
    float* zB = pool + 9437184;
    {
        int oT = N * 1024 * 9;
        outer_gemm<<<dim3(1, 144), BLK, 0, stream>>>(Wn5, zvec, nullptr, zA, 9216, 128, 1);
        bn_stats_kernel<<<1024, BLK, 0, stream>>>(zA, mean, rstd, N, 1024, 9);
        bn_act_kernel<<<gdiv(oT, BLK), BLK, 0, stream>>>(zA, mean, rstd, zB, oT, 1024, 9, 1, 1);
    }
    float* cur = zB;
    for (int i = 4; i >= 1; --i) {
        int oT = N * Cin[i] * Hin[i] * Hin[i];
        int xpixc = N * (Hin[i] / 2) * (Hin[i] / 2);
        int sk = SKt[i];
        if (sk == 1) {
            convt_gemm<<<dim3(xpixc / 64, Cin[i] / 64, 4), BLK, 0, stream>>>(
                Wkc[i], cur, nullptr, zA, Cin[i], Cout[i], Hout[i], Hout[i],
                Hin[i], Hin[i], 1, 1);
        } else {
            hipMemsetAsync(zA, 0, (size_t)oT * 4, stream);
            convt_gemm<<<dim3(xpixc / 64, Cin[i] / 64, 4 * sk), BLK, 0, stream>>>(
                Wkc[i], cur, nullptr, zA, Cin[i], Cout[i], Hout[i], Hout[i],
                Hin[i], Hin[i], 2, sk);
        }
        bn_stats_kernel<<<Cin[i], BLK, 0, stream>>>(zA, mean, rstd, N, Cin[i], Hin[i] * Hin[i]);
        bn_act_kernel<<<gdiv(oT, BLK), BLK, 0, stream>>>(zA, mean, rstd, zB, oT,
            Cin[i], Hin[i] * Hin[i], 1, 1);
        cur = zB;
    }
    convt_m3<<<dim3(N * 48 * 48 / BLK, 1, 4), BLK, 0, stream>>>(
        Wkc[0], cur, nullptr, out + 8192, 64, 48, 48, 96, 96, 2);
}

// Round 7
// 4318.816 us; speedup vs baseline: 25.9736x; 2.0917x over previous
//
#include <hip/hip_runtime.h>
#include <math.h>

#define BLK 256
static constexpr float MU_F  = 0.1f;
static constexpr float THR_F = 0.01f;

typedef __attribute__((ext_vector_type(8))) short bf16x8;
typedef __attribute__((ext_vector_type(4))) float f32x4;

__device__ inline unsigned short f2bf(float f) {
    unsigned u = __float_as_uint(f);
    unsigned r = (u + 0x7fffu + ((u >> 16) & 1u)) >> 16;   // RNE
    return (unsigned short)r;
}
__device__ inline float bf2f(unsigned short h) {
    return __uint_as_float(((unsigned)h) << 16);
}

// ---------------- block reduction ----------------
__device__ inline float blk_reduce(float v) {
    __shared__ float sh[BLK];
    int tid = threadIdx.x;
    sh[tid] = v;
    __syncthreads();
    #pragma unroll
    for (int s = BLK / 2; s > 0; s >>= 1) {
        if (tid < s) sh[tid] += sh[tid + s];
        __syncthreads();
    }
    float r = sh[0];
    __syncthreads();
    return r;
}

// ---------------- fp32 normalize + pack (L0, L5) ----------------
__global__ __launch_bounds__(BLK) void wnorm_pack(
    const float* __restrict__ W, float* __restrict__ Wkc,
    float* __restrict__ Wnout, int Mout, int asz)
{
    int o = blockIdx.x;
    const float* w = W + (size_t)o * asz;
    float s = 0.f;
    for (int i = threadIdx.x; i < asz; i += BLK) { float v = w[i]; s = fmaf(v, v, s); }
    float tot = blk_reduce(s);
    float inv = 1.0f / (sqrtf(tot) + 1e-12f);
    for (int i = threadIdx.x; i < asz; i += BLK) {
        float v = w[i] * inv;
        Wkc[(size_t)i * Mout + o] = v;
        if (Wnout) Wnout[(size_t)o * asz + i] = v;
    }
}

// ---------------- bf16x2(hi/lo) normalize + MFMA-fragment pack (L1..L4) ----------------
// Cpk layout: [hi: Ktot*M][lo: Ktot*M] with frag order [(k>>3)][m][k&7], Ktot=Cin*16, M=Cout
// Tpk layout: [hi: 4par][lo: 4par], per par [(q>>3)][c][q&7], q = o*4+tt, M=Cin
__global__ __launch_bounds__(BLK) void wnorm_pack_bf16(
    const float* __restrict__ W, short* __restrict__ Cpk, short* __restrict__ Tpk,
    int Cout, int Cin)
{
    int o = blockIdx.x;
    int asz = Cin * 16;
    const float* w = W + (size_t)o * asz;
    float s = 0.f;
    for (int i = threadIdx.x; i < asz; i += BLK) { float v = w[i]; s = fmaf(v, v, s); }
    float tot = blk_reduce(s);
    float inv = 1.0f / (sqrtf(tot) + 1e-12f);
    size_t cTot = (size_t)Cout * asz;           // hi-region size (shorts)
    size_t parStride = (size_t)Cout * 4 * Cin;
    size_t tTot = 4 * parStride;
    for (int i = threadIdx.x; i < asz; i += BLK) {
        float v = w[i] * inv;
        unsigned short hb = f2bf(v);
        unsigned short lb = f2bf(v - bf2f(hb));
        size_t cidx = ((size_t)(i >> 3)) * (Cout * 8) + o * 8 + (i & 7);
        Cpk[cidx] = (short)hb;
        Cpk[cTot + cidx] = (short)lb;
        int c = i >> 4, tap = i & 15, kh = tap >> 2, kw = tap & 3;
        int par = (1 - (kh & 1)) * 2 + (1 - (kw & 1));
        int tt = ((kh >> 1) << 1) | (kw >> 1);
        int q = o * 4 + tt;
        size_t tidx = (size_t)par * parStride + ((size_t)(q >> 3)) * (Cin * 8) + c * 8 + (q & 7);
        Tpk[tidx] = (short)hb;
        Tpk[tTot + tidx] = (short)lb;
    }
}

// ---------------- XCD-aware bijective swizzle ----------------
__device__ inline void xcd_remap(int& bx, int& by, int& bz) {
    int nx = gridDim.x, ny = gridDim.y;
    int nwg = nx * ny * gridDim.z;
    int orig = blockIdx.x + nx * (blockIdx.y + ny * blockIdx.z);
    int q8 = nwg >> 3, r8 = nwg & 7, xcd = orig & 7, sidx = orig >> 3;
    int w = (xcd < r8 ? xcd * (q8 + 1) : r8 * (q8 + 1) + (xcd - r8) * q8) + sidx;
    bx = w % nx; int t = w / nx; by = t % ny; bz = t / ny;
}

// ---------------- bf16x3 MFMA implicit-GEMM forward conv (K=4,S=2,P=1) ----------------
// acc = Whi*Xhi + Whi*Xlo + Wlo*Xhi  (fp32 accum)
// emode 0: relu(MU*acc-THR); 1: relu(yin+MU*acc-THR); 2: atomicAdd raw (split-K)
__global__ __launch_bounds__(BLK) void conv_gemm_bf16(
    const short* __restrict__ Wpk, const float* __restrict__ x,
    const float* __restrict__ yin, float* __restrict__ out,
    int M, int Cx, int Hx, int Wx, int Hout, int Wout,
    int kchunk, int emode)
{
    __shared__ __align__(16) short Wh[4][64][8];
    __shared__ __align__(16) short Wo_[4][64][8];
    __shared__ __align__(16) short Xh[4][64][8];
    __shared__ __align__(16) short Xo[4][64][8];
    int bx, by, bz; xcd_remap(bx, by, bz);
    int tid = threadIdx.x, lane = tid & 63, wid = tid >> 6;
    int HW = Hout * Wout, HWx = Hx * Wx;
    int pbase = bx * 64, m0 = by * 64, kb = bz * kchunk;
    size_t loOff = (size_t)Cx * 16 * M;

    int spl = tid & 63, skb = tid >> 6;
    int sp = pbase + spl;
    int sn = sp / HW; int srr = sp - sn * HW;
    int sho = srr / Wout, swo = srr - sho * Wout;
    const float* xs = x + (size_t)sn * Cx * HWx;
    int h0 = sho * 2 - 1, w0 = swo * 2 - 1;

    f32x4 acc[4] = {};
    for (int k0 = kb; k0 < kb + kchunk; k0 += 32) {
        size_t so = ((size_t)((k0 >> 3) + skb)) * (M * 8) + (size_t)m0 * 8 + spl * 8;
        *(float4*)(&Wh[skb][spl][0])  = *(const float4*)(Wpk + so);
        *(float4*)(&Wo_[skb][spl][0]) = *(const float4*)(Wpk + loOff + so);
        {
            int kbase = k0 + skb * 8;
            int ci = kbase >> 4;
            int t16 = kbase & 15;
            const float* xc = xs + (size_t)ci * HWx;
            union { short s[8]; float4 f; } uh, ul;
            #pragma unroll
            for (int jj = 0; jj < 8; ++jj) {
                int tap = t16 + jj;
                int kh = tap >> 2, kw = tap & 3;
                int h = h0 + kh, w = w0 + kw;
                float g = ((unsigned)h < (unsigned)Hx && (unsigned)w < (unsigned)Wx)
                        ? xc[h * Wx + w] : 0.f;
                unsigned short hb = f2bf(g);
                uh.s[jj] = (short)hb;
                ul.s[jj] = (short)f2bf(g - bf2f(hb));
            }
            *(float4*)(&Xh[skb][spl][0]) = uh.f;
            *(float4*)(&Xo[skb][spl][0]) = ul.f;
        }
        __syncthreads();
        bf16x8 ah = *(const bf16x8*)(&Wh[lane >> 4][wid * 16 + (lane & 15)][0]);
        bf16x8 al = *(const bf16x8*)(&Wo_[lane >> 4][wid * 16 + (lane & 15)][0]);
        #pragma unroll
        for (int nf = 0; nf < 4; ++nf) {
            bf16x8 bh = *(const bf16x8*)(&Xh[lane >> 4][nf * 16 + (lane & 15)][0]);
            bf16x8 bl = *(const bf16x8*)(&Xo[lane >> 4][nf * 16 + (lane & 15)][0]);
            acc[nf] = __builtin_amdgcn_mfma_f32_16x16x32_bf16(al, bh, acc[nf], 0, 0, 0);
            acc[nf] = __builtin_amdgcn_mfma_f32_16x16x32_bf16(ah, bl, acc[nf], 0, 0, 0);
            acc[nf] = __builtin_amdgcn_mfma_f32_16x16x32_bf16(ah, bh, acc[nf], 0, 0, 0);
        }
        __syncthreads();
    }
    int colp = lane & 15, rquad = lane >> 4;
    #pragma unroll
    for (int nf = 0; nf < 4; ++nf) {
        int p = pbase + nf * 16 + colp;
        int n = p / HW; int rr = p - n * HW;
        int ho = rr / Wout, wo = rr - ho * Wout;
        #pragma unroll
        for (int r = 0; r < 4; ++r) {
            int m = m0 + wid * 16 + rquad * 4 + r;
            size_t idx = (((size_t)n * M + m) * Hout + ho) * Wout + wo;
            float v = acc[nf][r];
            if (emode == 0)      out[idx] = fmaxf(MU_F * v - THR_F, 0.f);
            else if (emode == 1) out[idx] = fmaxf(yin[idx] + MU_F * v - THR_F, 0.f);
            else                 atomicAdd(&out[idx], v);
        }
    }
}

// ---------------- bf16x3 MFMA implicit-GEMM transpose conv ----------------
// grid.z = par*SK + chunk.  emode 0: aux-acc; 1: acc; 2: atomicAdd (split-K)
__global__ __launch_bounds__(BLK) void convt_gemm_bf16(
    const short* __restrict__ Wpk, const float* __restrict__ z,
    const float* __restrict__ aux, float* __restrict__ out,
    int M, int Cz, int Hz, int Wz, int Ho, int Wo, int emode, int SK)
{
    __shared__ __align__(16) short Wh[4][64][8];
    __shared__ __align__(16) short Wo_[4][64][8];
    __shared__ __align__(16) short Xh[4][64][8];
    __shared__ __align__(16) short Xo[4][64][8];
    int bx, by, bz; xcd_remap(bx, by, bz);
    int tid = threadIdx.x, lane = tid & 63, wid = tid >> 6;
    int par = bz / SK, chunk = bz - par * SK;
    int hbit = par >> 1, wbit = par & 1;
    int czs = Cz / SK;
    int qb = chunk * czs * 4;
    size_t parS = (size_t)Cz * 4 * M;
    const short* Wp = Wpk + (size_t)par * parS;
    size_t loOff = 4 * parS;
    int Hc = Ho >> 1, Wc = Wo >> 1, HWc = Hc * Wc;
    int pbase = bx * 64, m0 = by * 64;

    int spl = tid & 63, skb = tid >> 6;
    int sp = pbase + spl;
    int sn = sp / HWc; int srr = sp - sn * HWc;
    int shc = srr / Wc, swc = srr - shc * Wc;
    const float* zs = z + (size_t)sn * Cz * Hz * Wz;

    f32x4 acc[4] = {};
    for (int q0 = qb; q0 < qb + czs * 4; q0 += 32) {
        size_t so = ((size_t)((q0 >> 3) + skb)) * (M * 8) + (size_t)m0 * 8 + spl * 8;
        *(float4*)(&Wh[skb][spl][0])  = *(const float4*)(Wp + so);
        *(float4*)(&Wo_[skb][spl][0]) = *(const float4*)(Wp + loOff + so);
        {
            int qq = q0 + skb * 8;
            union { short s[8]; float4 f; } uh, ul;
            #pragma unroll
            for (int jj = 0; jj < 8; ++jj) {
                int q = qq + jj;
                int cz = q >> 2, tt = q & 3, ti = tt >> 1, tj = tt & 1;
                int hn = shc + hbit - ti, wn = swc + wbit - tj;
                float g = ((unsigned)hn < (unsigned)Hz && (unsigned)wn < (unsigned)Wz)
                        ? zs[((size_t)cz * Hz + hn) * Wz + wn] : 0.f;
                unsigned short hb = f2bf(g);
                uh.s[jj] = (short)hb;
                ul.s[jj] = (short)f2bf(g - bf2f(hb));
            }
            *(float4*)(&Xh[skb][spl][0]) = uh.f;
            *(float4*)(&Xo[skb][spl][0]) = ul.f;
        }
        __syncthreads();
        bf16x8 ah = *(const bf16x8*)(&Wh[lane >> 4][wid * 16 + (lane & 15)][0]);
        bf16x8 al = *(const bf16x8*)(&Wo_[lane >> 4][wid * 16 + (lane & 15)][0]);
        #pragma unroll
        for (int nf = 0; nf < 4; ++nf) {
            bf16x8 bh = *(const bf16x8*)(&Xh[lane >> 4][nf * 16 + (lane & 15)][0]);
            bf16x8 bl = *(const bf16x8*)(&Xo[lane >> 4][nf * 16 + (lane & 15)][0]);
            acc[nf] = __builtin_amdgcn_mfma_f32_16x16x32_bf16(al, bh, acc[nf], 0, 0, 0);
            acc[nf] = __builtin_amdgcn_mfma_f32_16x16x32_bf16(ah, bl, acc[nf], 0, 0, 0);
            acc[nf] = __builtin_amdgcn_mfma_f32_16x16x32_bf16(ah, bh, acc[nf], 0, 0, 0);
        }
        __syncthreads();
    }
    int colp = lane & 15, rquad = lane >> 4;
    #pragma unroll
    for (int nf = 0; nf < 4; ++nf) {
        int p = pbase + nf * 16 + colp;
        int n = p / HWc; int rr = p - n * HWc;
        int hc = rr / Wc, wc = rr - hc * Wc;
        int ho = 2 * hc + hbit, wo = 2 * wc + wbit;
        #pragma unroll
        for (int r = 0; r < 4; ++r) {
            int m = m0 + wid * 16 + rquad * 4 + r;
            size_t idx = (((size_t)n * M + m) * Ho + ho) * Wo + wo;
            float v = acc[nf][r];
            if (emode == 0)      out[idx] = aux[idx] - v;
            else if (emode == 1) out[idx] = v;
            else                 atomicAdd(&out[idx], v);
        }
    }
}

// ---------------- fp32 implicit-GEMM forward conv (L0, L5) ----------------
template <int KK, int Kk, int S, int P>
__global__ __launch_bounds__(BLK) void conv_gemm(
    const float* __restrict__ Wp, const float* __restrict__ x,
    const float* __restrict__ yin, float* __restrict__ out,
    int M, int Ktot, int Cx, int Hx, int Wx, int Hout, int Wout,
    int kchunk, int emode)
{
    __shared__ float Wt[16][64];
    __shared__ float Xt[16][64];
    int tid = threadIdx.x, tx = tid & 15, ty = tid >> 4;
    int HW = Hout * Wout, HWx = Hx * Wx;
    int pbase = blockIdx.x * 64 + tx * 4;
    int n_[4], ho_[4], wo_[4];
    const float* xb_[4];
    #pragma unroll
    for (int j = 0; j < 4; ++j) {
        int p = pbase + j; int n = p / HW; int r = p - n * HW;
        int ho = r / Wout; int wo = r - ho * Wout;
        n_[j] = n; ho_[j] = ho; wo_[j] = wo;
        xb_[j] = x + (size_t)n * Cx * HWx;
    }
    int m0 = blockIdx.y * 64;
    int kb = blockIdx.z * kchunk, ke = kb + kchunk;
    if (ke > Ktot) ke = Ktot;
    float acc[4][4] = {};
    for (int k0 = kb; k0 < ke; k0 += 16) {
        int kr = k0 + ty;
        *(float4*)&Wt[ty][tx * 4] = *(const float4*)&Wp[(size_t)kr * M + m0 + tx * 4];
        int ci = kr / KK; int t = kr - ci * KK; int kh = t / Kk; int kw = t - kh * Kk;
        int cio = ci * HWx;
        float g[4];
        #pragma unroll
        for (int j = 0; j < 4; ++j) {
            int h = ho_[j] * S - P + kh, w = wo_[j] * S - P + kw;
            g[j] = ((unsigned)h < (unsigned)Hx && (unsigned)w < (unsigned)Wx)
                 ? xb_[j][cio + h * Wx + w] : 0.f;
        }
        *(float4*)&Xt[ty][tx * 4] = make_float4(g[0], g[1], g[2], g[3]);
        __syncthreads();
        #pragma unroll
        for (int kk = 0; kk < 16; ++kk) {
            float4 a = *(float4*)&Wt[kk][ty * 4];
            float4 b = *(float4*)&Xt[kk][tx * 4];
            float aa[4] = {a.x, a.y, a.z, a.w};
            float bb[4] = {b.x, b.y, b.z, b.w};
            #pragma unroll
            for (int i = 0; i < 4; ++i)
                #pragma unroll
                for (int j = 0; j < 4; ++j)
                    acc[i][j] = fmaf(aa[i], bb[j], acc[i][j]);
        }
        __syncthreads();
    }
    #pragma unroll
    for (int i = 0; i < 4; ++i) {
        int m = m0 + ty * 4 + i;
        #pragma unroll
        for (int j = 0; j < 4; ++j) {
            size_t idx = (((size_t)n_[j] * M + m) * Hout + ho_[j]) * Wout + wo_[j];
            float v = acc[i][j];
            if (emode == 0)      out[idx] = fmaxf(MU_F * v - THR_F, 0.f);
            else if (emode == 1) out[idx] = fmaxf(yin[idx] + MU_F * v - THR_F, 0.f);
            else                 atomicAdd(&out[idx], v);
        }
    }
}

// ---------------- 1x1-source transpose conv as plain GEMM (L5) ----------------
__global__ __launch_bounds__(BLK) void outer_gemm(
    const float* __restrict__ Wp, const float* __restrict__ zin,
    const float* __restrict__ aux, float* __restrict__ out,
    int M, int Kz, int emode)
{
    __shared__ float Wt[16][64];
    __shared__ float Xt[16][64];
    int tid = threadIdx.x, tx = tid & 15, ty = tid >> 4;
    int m0 = blockIdx.y * 64;
    float acc[4][4] = {};
    for (int k0 = 0; k0 < Kz; k0 += 16) {
        int kr = k0 + ty;
        *(float4*)&Wt[ty][tx * 4] = *(const float4*)&Wp[(size_t)kr * M + m0 + tx * 4];
        float g[4];
        #pragma unroll
        for (int j = 0; j < 4; ++j) g[j] = zin[(size_t)(tx * 4 + j) * Kz + kr];
        *(float4*)&Xt[ty][tx * 4] = make_float4(g[0], g[1], g[2], g[3]);
        __syncthreads();
        #pragma unroll
        for (int kk = 0; kk < 16; ++kk) {
            float4 a = *(float4*)&Wt[kk][ty * 4];
            float4 b = *(float4*)&Xt[kk][tx * 4];
            float aa[4] = {a.x, a.y, a.z, a.w};
            float bb[4] = {b.x, b.y, b.z, b.w};
            #pragma unroll
            for (int i = 0; i < 4; ++i)
                #pragma unroll
                for (int j = 0; j < 4; ++j)
                    acc[i][j] = fmaf(aa[i], bb[j], acc[i][j]);
        }
        __syncthreads();
    }
    #pragma unroll
    for (int i = 0; i < 4; ++i) {
        int m = m0 + ty * 4 + i;
        #pragma unroll
        for (int j = 0; j < 4; ++j) {
            int n = tx * 4 + j;
            size_t idx = (size_t)n * M + m;
            float v = acc[i][j];
            out[idx] = (emode == 0) ? (aux[idx] - v) : v;
        }
    }
}

// ---------------- M=3 transpose conv (image space, fp32) ----------------
__global__ __launch_bounds__(BLK) void convt_m3(
    const float* __restrict__ Wkc0, const float* __restrict__ z,
    const float* __restrict__ aux, float* __restrict__ out,
    int Cz, int Hz, int Wz, int Ho, int Wo, int emode)
{
    __shared__ float Wl[64 * 4 * 3];
    int tid = threadIdx.x;
    int hbit = blockIdx.z >> 1, wbit = blockIdx.z & 1;
    int khp = 1 - hbit, kwp = 1 - wbit;
    int Ktot = Cz * 4;
    for (int kidx = tid; kidx < Ktot; kidx += BLK) {
        int cz = kidx >> 2, t = kidx & 3, ti = t >> 1, tj = t & 1;
        int tap = (khp + 2 * ti) * 4 + (kwp + 2 * tj);
        Wl[kidx * 3 + 0] = Wkc0[(0 * 16 + tap) * 64 + cz];
        Wl[kidx * 3 + 1] = Wkc0[(1 * 16 + tap) * 64 + cz];
        Wl[kidx * 3 + 2] = Wkc0[(2 * 16 + tap) * 64 + cz];
    }
    __syncthreads();
    int Hc = Ho >> 1, Wc = Wo >> 1, HWc = Hc * Wc;
    int p = blockIdx.x * BLK + tid;
    int n = p / HWc, r = p - n * HWc, hc = r / Wc, wc = r - (r / Wc) * Wc;
    const float* zb = z + (size_t)n * Cz * Hz * Wz;
    int offs[4]; bool val[4];
    #pragma unroll
    for (int t = 0; t < 4; ++t) {
        int ti = t >> 1, tj = t & 1;
        int hn = hc + hbit - ti, wn = wc + wbit - tj;
        val[t] = ((unsigned)hn < (unsigned)Hz) && ((unsigned)wn < (unsigned)Wz);
        offs[t] = hn * Wz + wn;
    }
    float a0 = 0.f, a1 = 0.f, a2 = 0.f;
    int HWz = Hz * Wz;
    for (int cz = 0; cz < Cz; ++cz) {
        const float* base = zb + cz * HWz;
        #pragma unroll
        for (int t = 0; t < 4; ++t) {
            float g = val[t] ? base[offs[t]] : 0.f;
            int wi = (cz * 4 + t) * 3;
            a0 = fmaf(g, Wl[wi + 0], a0);
            a1 = fmaf(g, Wl[wi + 1], a1);
            a2 = fmaf(g, Wl[wi + 2], a2);
        }
    }
    int ho = 2 * hc + hbit, wo = 2 * wc + wbit;
    #pragma unroll
    for (int u = 0; u < 3; ++u) {
        float v = (u == 0) ? a0 : (u == 1) ? a1 : a2;
        size_t idx = (((size_t)n * 3 + u) * Ho + ho) * Wo + wo;
        out[idx] = (emode == 0) ? (aux[idx] - v) : tanhf(v);
    }
}

// ---------------- epilogues / elementwise ----------------
__global__ __launch_bounds__(BLK) void shrink_epi(
    const float* __restrict__ p, const float* __restrict__ y,
    float* __restrict__ o, int n, int mode)
{
    int i = blockIdx.x * BLK + threadIdx.x;
    if (i >= n) return;
    float v = MU_F * p[i] - THR_F;
    if (mode == 1) v += y[i];
    o[i] = fmaxf(v, 0.f);
}

__global__ __launch_bounds__(BLK) void res_epi(
    const float* __restrict__ aux, const float* __restrict__ acc,
    float* __restrict__ o, int n)
{
    int i = blockIdx.x * BLK + threadIdx.x;
    if (i >= n) return;
    o[i] = aux[i] - acc[i];
}

__global__ __launch_bounds__(BLK) void y_update_kernel(
    const float* __restrict__ z, const float* __restrict__ zo,
    float* __restrict__ y, int total, float c)
{
    int i = blockIdx.x * BLK + threadIdx.x;
    if (i >= total) return;
    float zv = z[i];
    y[i] = fmaf(c, zv - zo[i], zv);
}

__global__ __launch_bounds__(BLK) void bn_stats_kernel(
    const float* __restrict__ x, float* __restrict__ mean, float* __restrict__ rstd,
    int N, int C, int HW)
{
    int c = blockIdx.x;
    int cnt = N * HW;
    float s = 0.f, s2 = 0.f;
    for (int i = threadIdx.x; i < cnt; i += BLK) {
        int n = i / HW, hw = i - n * HW;
        float v = x[((size_t)n * C + c) * HW + hw];
        s += v; s2 = fmaf(v, v, s2);
    }
    float ts  = blk_reduce(s);
    float ts2 = blk_reduce(s2);
    if (threadIdx.x == 0) {
        float m = ts / cnt;
        float var = ts2 / cnt - m * m;
        mean[c] = m;
        rstd[c] = rsqrtf(var + 1e-5f);
    }
}

__global__ __launch_bounds__(BLK) void bn_act_kernel(
    const float* __restrict__ x, const float* __restrict__ mean,
    const float* __restrict__ rstd, float* __restrict__ out,
    int total, int C, int HW, int use_bn, int act)
{
    int i = blockIdx.x * BLK + threadIdx.x;
    if (i >= total) return;
    float v = x[i];
    if (use_bn) { int c = (i / HW) % C; v = (v - mean[c]) * rstd[c]; }
    out[i] = (act == 0) ? ((v >= 0.f) ? v : 0.2f * v) : fmaxf(v, 0.f);
}

__global__ __launch_bounds__(128) void rownorm_kernel(
    const float* __restrict__ z, float* __restrict__ out, float* __restrict__ zvec)
{
    __shared__ float sh[128];
    int r = blockIdx.x, tid = threadIdx.x;
    float v = z[r * 128 + tid];
    sh[tid] = v * v;
    __syncthreads();
    #pragma unroll
    for (int s = 64; s > 0; s >>= 1) {
        if (tid < s) sh[tid] += sh[tid + s];
        __syncthreads();
    }
    float nrm = fmaxf(sqrtf(sh[0]), 1e-12f);
    float o = v / nrm;
    out[r * 128 + tid] = o;
    zvec[r * 128 + tid] = o;
}

static inline int gdiv(int a, int b) { return (a + b - 1) / b; }

extern "C" void kernel_launch(void* const* d_in, const int* in_sizes, int n_in,
                              void* d_out, int out_size, void* d_ws, size_t ws_size,
                              hipStream_t stream)
{
    const float* x = (const float*)d_in[0];
    const float* W[6];
    for (int i = 0; i < 6; ++i) W[i] = (const float*)d_in[1 + i];
    float* ws  = (float*)d_ws;
    float* out = (float*)d_out;

    const int Cin[6]  = {3, 64, 128, 256, 512, 1024};
    const int Cout[6] = {64, 128, 256, 512, 1024, 128};
    const int Hin[6]  = {96, 48, 24, 12, 6, 3};
    const int Hout[6] = {48, 24, 12, 6, 3, 1};
    const int N = 64;
    const int SKc[6] = {1, 1, 2, 4, 8, 1};
    const int SKt[6] = {1, 1, 1, 2, 4, 1};

    // ---- workspace layout: 66,532,352 floats = 253.8 MB (same as round 6, which ran) ----
    size_t off = 0;
    float* Wkc0 = ws + off; off += 3072;
    float* Wkc5 = ws + off; off += 1179648;
    float* Wn5  = ws + off; off += 1179648;
    const size_t csz[5] = {0, 131072, 524288, 2097152, 8388608};
    // bf16 hi+lo packs (shorts) for L1..L4: each region is 2*csz[L]
    short* Cpk[5]; short* Tpk[5];
    {
        short* sbase = (short*)(ws + off);
        size_t soff = 0;
        for (int L = 1; L < 5; ++L) { Cpk[L] = sbase + soff; soff += 2 * csz[L]; }
        for (int L = 1; L < 5; ++L) { Tpk[L] = sbase + soff; soff += 2 * csz[L]; }
        off += soff / 2;          // 44,564,480 shorts -> 22,282,240 floats
    }
    const size_t POOL = 30081024;
    float* pool = ws + off; off += POOL;
    float* xb   = ws + off; off += 9437184;
    float* mean = ws + off; off += 1024;
    float* rstd = ws + off; off += 1024;
    float* zvec = ws + off; off += 8192;
    float* pbuf = ws + off; off += 2359296;

    // ---- normalize + pack dictionaries ----
    wnorm_pack<<<64, BLK, 0, stream>>>(W[0], Wkc0, nullptr, 64, 48);
    for (int L = 1; L < 5; ++L)
        wnorm_pack_bf16<<<Cout[L], BLK, 0, stream>>>(W[L], Cpk[L], Tpk[L], Cout[L], Cin[L]);
    wnorm_pack<<<128, BLK, 0, stream>>>(W[5], Wkc5, Wn5, 128, 9216);

    // ---- FISTA momentum coefficients ----
    double td = 1.0; float cc[3];
    for (int i = 0; i < 3; ++i) {
        double tn = (1.0 + sqrt(1.0 + 4.0 * td * td)) * 0.5;
        cc[i] = (float)((td - 1.0) / tn);
        td = tn;
    }

    const float* in = x;
    for (int L = 0; L < 6; ++L) {
        int zTot = N * Cout[L] * Hout[L] * Hout[L];
        int xTot = N * Cin[L] * Hin[L] * Hin[L];
        int npix = N * Hout[L] * Hout[L];
        dim3 ge(gdiv(zTot, BLK));
        dim3 gr(gdiv(xTot, BLK));

        float* zA = pool;
        float* zB = pool + (size_t)zTot;
        float* yb = pool + (size_t)2 * zTot;
        float* rb = pool + (size_t)3 * zTot;

        auto launch_conv = [&](const float* src, const float* y, float* dst, int mode) {
            if (L == 5) {
                hipMemsetAsync(pbuf, 0, (size_t)zTot * 4, stream);
                conv_gemm<9, 3, 1, 0><<<dim3(1, 2, 72), BLK, 0, stream>>>(Wkc5, src,
                    nullptr, pbuf, 128, 9216, 1024, 3, 3, 1, 1, 128, 2);
                shrink_epi<<<gdiv(zTot, BLK), BLK, 0, stream>>>(pbuf, y, dst, zTot, mode);
            } else if (L == 0) {
                conv_gemm<16, 4, 2, 1><<<dim3(npix / 64, 1), BLK, 0, stream>>>(
                    Wkc0, src, y, dst, 64, 48, 3, 96, 96, 48, 48, 48, mode);
            } else if (SKc[L] == 1) {
                conv_gemm_bf16<<<dim3(npix / 64, Cout[L] / 64), BLK, 0, stream>>>(
                    Cpk[L], src, y, dst, Cout[L], Cin[L], Hin[L], Hin[L],
                    Hout[L], Hout[L], Cin[L] * 16, mode);
            } else {
                int sk = SKc[L];
                hipMemsetAsync(pbuf, 0, (size_t)zTot * 4, stream);
                conv_gemm_bf16<<<dim3(npix / 64, Cout[L] / 64, sk), BLK, 0, stream>>>(
                    Cpk[L], src, nullptr, pbuf, Cout[L], Cin[L], Hin[L], Hin[L],
                    Hout[L], Hout[L], Cin[L] * 16 / sk, 2);
                shrink_epi<<<gdiv(zTot, BLK), BLK, 0, stream>>>(pbuf, y, dst, zTot, mode);
            }
        };

        // z0 = shrink(MU * conv(in))
        launch_conv(in, nullptr, zA, 0);

        float* z = zA; float* zo = zB;
        for (int it = 0; it < 3; ++it) {
            const float* zold = (it == 0) ? z : zo;
            y_update_kernel<<<ge, BLK, 0, stream>>>(z, zold, yb, zTot, cc[it]);
            // r = in - convT(y)
            if (L == 0) {
                convt_m3<<<dim3(N * 48 * 48 / BLK, 1, 4), BLK, 0, stream>>>(
                    Wkc0, yb, in, rb, 64, 48, 48, 96, 96, 0);
            } else if (L < 5) {
                int xpixc = N * (Hin[L] / 2) * (Hin[L] / 2);
                int sk = SKt[L];
                if (sk == 1) {
                    convt_gemm_bf16<<<dim3(xpixc / 64, Cin[L] / 64, 4), BLK, 0, stream>>>(
                        Tpk[L], yb, in, rb, Cin[L], Cout[L], Hout[L], Hout[L],
                        Hin[L], Hin[L], 0, 1);
                } else {
                    hipMemsetAsync(rb, 0, (size_t)xTot * 4, stream);
                    convt_gemm_bf16<<<dim3(xpixc / 64, Cin[L] / 64, 4 * sk), BLK, 0, stream>>>(
                        Tpk[L], yb, nullptr, rb, Cin[L], Cout[L], Hout[L], Hout[L],
                        Hin[L], Hin[L], 2, sk);
                    res_epi<<<gr, BLK, 0, stream>>>(in, rb, rb, xTot);
                }
            } else {
                outer_gemm<<<dim3(1, 144), BLK, 0, stream>>>(Wn5, yb, in, rb, 9216, 128, 0);
            }
            // z_new = shrink(y + MU*conv(r))
            launch_conv(rb, yb, zo, 1);
            float* tmp = z; z = zo; zo = tmp;
        }

        int HW = Hout[L] * Hout[L];
        if (L == 0) {
            bn_act_kernel<<<ge, BLK, 0, stream>>>(z, nullptr, nullptr, xb, zTot, Cout[L], HW, 0, 0);
            in = xb;
        } else if (L < 5) {
            bn_stats_kernel<<<Cout[L], BLK, 0, stream>>>(z, mean, rstd, N, Cout[L], HW);
            bn_act_kernel<<<ge, BLK, 0, stream>>>(z, mean, rstd, xb, zTot, Cout[L], HW, 1, 0);
            in = xb;
        } else {
            rownorm_kernel<<<64, 128, 0, stream>>>(z, out, zvec);
        }
    }

    // ---- decoder (bf16x3 convT for stages 4..1, fp32 elsewhere) ----
    float* zA = pool;
    float* zB = pool + 9437184;
    {
        int oT = N * 1024 * 9;
        outer_gemm<<<dim3(1, 144), BLK, 0, stream>>>(Wn5, zvec, nullptr, zA, 9216, 128, 1);
        bn_stats_kernel<<<1024, BLK, 0, stream>>>(zA, mean, rstd, N, 1024, 9);
        bn_act_kernel<<<gdiv(oT, BLK), BLK, 0, stream>>>(zA, mean, rstd, zB, oT, 1024, 9, 1, 1);
    }
    float* cur = zB;
    for (int i = 4; i >= 1; --i) {
        int oT = N * Cin[i] * Hin[i] * Hin[i];
        int xpixc = N * (Hin[i] / 2) * (Hin[i] / 2);
        int sk = SKt[i];
        if (sk == 1) {
            convt_gemm_bf16<<<dim3(xpixc / 64, Cin[i] / 64, 4), BLK, 0, stream>>>(
                Tpk[i], cur, nullptr, zA, Cin[i], Cout[i], Hout[i], Hout[i],
                Hin[i], Hin[i], 1, 1);
        } else {
            hipMemsetAsync(zA, 0, (size_t)oT * 4, stream);
            convt_gemm_bf16<<<dim3(xpixc / 64, Cin[i] / 64, 4 * sk), BLK, 0, stream>>>(
                Tpk[i], cur, nullptr, zA, Cin[i], Cout[i], Hout[i], Hout[i],
                Hin[i], Hin[i], 2, sk);
        }
        bn_stats_kernel<<<Cin[i], BLK, 0, stream>>>(zA, mean, rstd, N, Cin[i], Hin[i] * Hin[i]);
        bn_act_kernel<<<gdiv(oT, BLK), BLK, 0, stream>>>(zA, mean, rstd, zB, oT,
            Cin[i], Hin[i] * Hin[i], 1, 1);
        cur = zB;
    }
    convt_m3<<<dim3(N * 48 * 48 / BLK, 1, 4), BLK, 0, stream>>>(
        Wkc0, cur, nullptr, out + 8192, 64, 48, 48, 96, 96, 2);
}

// Round 8
// 3985.127 us; speedup vs baseline: 28.1484x; 1.0837x over previous
//
#include <hip/hip_runtime.h>
#include <math.h>

#define BLK 256
static constexpr float MU_F  = 0.1f;
static constexpr float THR_F = 0.01f;

typedef __attribute__((ext_vector_type(8))) short bf16x8;
typedef __attribute__((ext_vector_type(4))) float f32x4;

__device__ inline unsigned short f2bf(float f) {
    unsigned u = __float_as_uint(f);
    unsigned r = (u + 0x7fffu + ((u >> 16) & 1u)) >> 16;   // RNE
    return (unsigned short)r;
}
__device__ inline float bf2f(unsigned short h) {
    return __uint_as_float(((unsigned)h) << 16);
}

// ---------------- block reduction ----------------
__device__ inline float blk_reduce(float v) {
    __shared__ float sh[BLK];
    int tid = threadIdx.x;
    sh[tid] = v;
    __syncthreads();
    #pragma unroll
    for (int s = BLK / 2; s > 0; s >>= 1) {
        if (tid < s) sh[tid] += sh[tid + s];
        __syncthreads();
    }
    float r = sh[0];
    __syncthreads();
    return r;
}

// ---------------- fp32 normalize + pack (L0, L5) ----------------
__global__ __launch_bounds__(BLK) void wnorm_pack(
    const float* __restrict__ W, float* __restrict__ Wkc,
    float* __restrict__ Wnout, int Mout, int asz)
{
    int o = blockIdx.x;
    const float* w = W + (size_t)o * asz;
    float s = 0.f;
    for (int i = threadIdx.x; i < asz; i += BLK) { float v = w[i]; s = fmaf(v, v, s); }
    float tot = blk_reduce(s);
    float inv = 1.0f / (sqrtf(tot) + 1e-12f);
    for (int i = threadIdx.x; i < asz; i += BLK) {
        float v = w[i] * inv;
        Wkc[(size_t)i * Mout + o] = v;
        if (Wnout) Wnout[(size_t)o * asz + i] = v;
    }
}

// ---------------- bf16x2(hi/lo) normalize + MFMA-fragment pack (L1..L4) ----------------
__global__ __launch_bounds__(BLK) void wnorm_pack_bf16(
    const float* __restrict__ W, short* __restrict__ Cpk, short* __restrict__ Tpk,
    int Cout, int Cin)
{
    int o = blockIdx.x;
    int asz = Cin * 16;
    const float* w = W + (size_t)o * asz;
    float s = 0.f;
    for (int i = threadIdx.x; i < asz; i += BLK) { float v = w[i]; s = fmaf(v, v, s); }
    float tot = blk_reduce(s);
    float inv = 1.0f / (sqrtf(tot) + 1e-12f);
    size_t cTot = (size_t)Cout * asz;
    size_t parStride = (size_t)Cout * 4 * Cin;
    size_t tTot = 4 * parStride;
    for (int i = threadIdx.x; i < asz; i += BLK) {
        float v = w[i] * inv;
        unsigned short hb = f2bf(v);
        unsigned short lb = f2bf(v - bf2f(hb));
        size_t cidx = ((size_t)(i >> 3)) * (Cout * 8) + o * 8 + (i & 7);
        Cpk[cidx] = (short)hb;
        Cpk[cTot + cidx] = (short)lb;
        int c = i >> 4, tap = i & 15, kh = tap >> 2, kw = tap & 3;
        int par = (1 - (kh & 1)) * 2 + (1 - (kw & 1));
        int tt = ((kh >> 1) << 1) | (kw >> 1);
        int q = o * 4 + tt;
        size_t tidx = (size_t)par * parStride + ((size_t)(q >> 3)) * (Cin * 8) + c * 8 + (q & 7);
        Tpk[tidx] = (short)hb;
        Tpk[tTot + tidx] = (short)lb;
    }
}

// ---------------- XCD-aware bijective swizzle ----------------
__device__ inline void xcd_remap(int& bx, int& by, int& bz) {
    int nx = gridDim.x, ny = gridDim.y;
    int nwg = nx * ny * gridDim.z;
    int orig = blockIdx.x + nx * (blockIdx.y + ny * blockIdx.z);
    int q8 = nwg >> 3, r8 = nwg & 7, xcd = orig & 7, sidx = orig >> 3;
    int w = (xcd < r8 ? xcd * (q8 + 1) : r8 * (q8 + 1) + (xcd - r8) * q8) + sidx;
    bx = w % nx; int t = w / nx; by = t % ny; bz = t / ny;
}

// ---------------- bf16x3 MFMA implicit-GEMM forward conv (K=4,S=2,P=1) ----------------
__global__ __launch_bounds__(BLK) void conv_gemm_bf16(
    const short* __restrict__ Wpk, const float* __restrict__ x,
    const float* __restrict__ yin, float* __restrict__ out,
    int M, int Cx, int Hx, int Wx, int Hout, int Wout,
    int kchunk, int emode)
{
    __shared__ __align__(16) short Wh[4][64][8];
    __shared__ __align__(16) short Wo_[4][64][8];
    __shared__ __align__(16) short Xh[4][64][8];
    __shared__ __align__(16) short Xo[4][64][8];
    int bx, by, bz; xcd_remap(bx, by, bz);
    int tid = threadIdx.x, lane = tid & 63, wid = tid >> 6;
    int HW = Hout * Wout, HWx = Hx * Wx;
    int pbase = bx * 64, m0 = by * 64, kb = bz * kchunk;
    size_t loOff = (size_t)Cx * 16 * M;

    int spl = tid & 63, skb = tid >> 6;
    int sp = pbase + spl;
    int sn = sp / HW; int srr = sp - sn * HW;
    int sho = srr / Wout, swo = srr - sho * Wout;
    const float* xs = x + (size_t)sn * Cx * HWx;
    int h0 = sho * 2 - 1, w0 = swo * 2 - 1;

    f32x4 acc[4] = {};
    for (int k0 = kb; k0 < kb + kchunk; k0 += 32) {
        size_t so = ((size_t)((k0 >> 3) + skb)) * (M * 8) + (size_t)m0 * 8 + spl * 8;
        *(float4*)(&Wh[skb][spl][0])  = *(const float4*)(Wpk + so);
        *(float4*)(&Wo_[skb][spl][0]) = *(const float4*)(Wpk + loOff + so);
        {
            int kbase = k0 + skb * 8;
            int ci = kbase >> 4;
            int t16 = kbase & 15;
            const float* xc = xs + (size_t)ci * HWx;
            union { short s[8]; float4 f; } uh, ul;
            #pragma unroll
            for (int jj = 0; jj < 8; ++jj) {
                int tap = t16 + jj;
                int kh = tap >> 2, kw = tap & 3;
                int h = h0 + kh, w = w0 + kw;
                float g = ((unsigned)h < (unsigned)Hx && (unsigned)w < (unsigned)Wx)
                        ? xc[h * Wx + w] : 0.f;
                unsigned short hb = f2bf(g);
                uh.s[jj] = (short)hb;
                ul.s[jj] = (short)f2bf(g - bf2f(hb));
            }
            *(float4*)(&Xh[skb][spl][0]) = uh.f;
            *(float4*)(&Xo[skb][spl][0]) = ul.f;
        }
        __syncthreads();
        bf16x8 ah = *(const bf16x8*)(&Wh[lane >> 4][wid * 16 + (lane & 15)][0]);
        bf16x8 al = *(const bf16x8*)(&Wo_[lane >> 4][wid * 16 + (lane & 15)][0]);
        #pragma unroll
        for (int nf = 0; nf < 4; ++nf) {
            bf16x8 bh = *(const bf16x8*)(&Xh[lane >> 4][nf * 16 + (lane & 15)][0]);
            bf16x8 bl = *(const bf16x8*)(&Xo[lane >> 4][nf * 16 + (lane & 15)][0]);
            acc[nf] = __builtin_amdgcn_mfma_f32_16x16x32_bf16(al, bh, acc[nf], 0, 0, 0);
            acc[nf] = __builtin_amdgcn_mfma_f32_16x16x32_bf16(ah, bl, acc[nf], 0, 0, 0);
            acc[nf] = __builtin_amdgcn_mfma_f32_16x16x32_bf16(ah, bh, acc[nf], 0, 0, 0);
        }
        __syncthreads();
    }
    int colp = lane & 15, rquad = lane >> 4;
    #pragma unroll
    for (int nf = 0; nf < 4; ++nf) {
        int p = pbase + nf * 16 + colp;
        int n = p / HW; int rr = p - n * HW;
        int ho = rr / Wout, wo = rr - ho * Wout;
        #pragma unroll
        for (int r = 0; r < 4; ++r) {
            int m = m0 + wid * 16 + rquad * 4 + r;
            size_t idx = (((size_t)n * M + m) * Hout + ho) * Wout + wo;
            float v = acc[nf][r];
            if (emode == 0)      out[idx] = fmaxf(MU_F * v - THR_F, 0.f);
            else if (emode == 1) out[idx] = fmaxf(yin[idx] + MU_F * v - THR_F, 0.f);
            else                 atomicAdd(&out[idx], v);
        }
    }
}

// ---------------- bf16x3 MFMA implicit-GEMM transpose conv ----------------
__global__ __launch_bounds__(BLK) void convt_gemm_bf16(
    const short* __restrict__ Wpk, const float* __restrict__ z,
    const float* __restrict__ aux, float* __restrict__ out,
    int M, int Cz, int Hz, int Wz, int Ho, int Wo, int emode, int SK)
{
    __shared__ __align__(16) short Wh[4][64][8];
    __shared__ __align__(16) short Wo_[4][64][8];
    __shared__ __align__(16) short Xh[4][64][8];
    __shared__ __align__(16) short Xo[4][64][8];
    int bx, by, bz; xcd_remap(bx, by, bz);
    int tid = threadIdx.x, lane = tid & 63, wid = tid >> 6;
    int par = bz / SK, chunk = bz - par * SK;
    int hbit = par >> 1, wbit = par & 1;
    int czs = Cz / SK;
    int qb = chunk * czs * 4;
    size_t parS = (size_t)Cz * 4 * M;
    const short* Wp = Wpk + (size_t)par * parS;
    size_t loOff = 4 * parS;
    int Hc = Ho >> 1, Wc = Wo >> 1, HWc = Hc * Wc;
    int pbase = bx * 64, m0 = by * 64;

    int spl = tid & 63, skb = tid >> 6;
    int sp = pbase + spl;
    int sn = sp / HWc; int srr = sp - sn * HWc;
    int shc = srr / Wc, swc = srr - shc * Wc;
    const float* zs = z + (size_t)sn * Cz * Hz * Wz;

    f32x4 acc[4] = {};
    for (int q0 = qb; q0 < qb + czs * 4; q0 += 32) {
        size_t so = ((size_t)((q0 >> 3) + skb)) * (M * 8) + (size_t)m0 * 8 + spl * 8;
        *(float4*)(&Wh[skb][spl][0])  = *(const float4*)(Wp + so);
        *(float4*)(&Wo_[skb][spl][0]) = *(const float4*)(Wp + loOff + so);
        {
            int qq = q0 + skb * 8;
            union { short s[8]; float4 f; } uh, ul;
            #pragma unroll
            for (int jj = 0; jj < 8; ++jj) {
                int q = qq + jj;
                int cz = q >> 2, tt = q & 3, ti = tt >> 1, tj = tt & 1;
                int hn = shc + hbit - ti, wn = swc + wbit - tj;
                float g = ((unsigned)hn < (unsigned)Hz && (unsigned)wn < (unsigned)Wz)
                        ? zs[((size_t)cz * Hz + hn) * Wz + wn] : 0.f;
                unsigned short hb = f2bf(g);
                uh.s[jj] = (short)hb;
                ul.s[jj] = (short)f2bf(g - bf2f(hb));
            }
            *(float4*)(&Xh[skb][spl][0]) = uh.f;
            *(float4*)(&Xo[skb][spl][0]) = ul.f;
        }
        __syncthreads();
        bf16x8 ah = *(const bf16x8*)(&Wh[lane >> 4][wid * 16 + (lane & 15)][0]);
        bf16x8 al = *(const bf16x8*)(&Wo_[lane >> 4][wid * 16 + (lane & 15)][0]);
        #pragma unroll
        for (int nf = 0; nf < 4; ++nf) {
            bf16x8 bh = *(const bf16x8*)(&Xh[lane >> 4][nf * 16 + (lane & 15)][0]);
            bf16x8 bl = *(const bf16x8*)(&Xo[lane >> 4][nf * 16 + (lane & 15)][0]);
            acc[nf] = __builtin_amdgcn_mfma_f32_16x16x32_bf16(al, bh, acc[nf], 0, 0, 0);
            acc[nf] = __builtin_amdgcn_mfma_f32_16x16x32_bf16(ah, bl, acc[nf], 0, 0, 0);
            acc[nf] = __builtin_amdgcn_mfma_f32_16x16x32_bf16(ah, bh, acc[nf], 0, 0, 0);
        }
        __syncthreads();
    }
    int colp = lane & 15, rquad = lane >> 4;
    #pragma unroll
    for (int nf = 0; nf < 4; ++nf) {
        int p = pbase + nf * 16 + colp;
        int n = p / HWc; int rr = p - n * HWc;
        int hc = rr / Wc, wc = rr - hc * Wc;
        int ho = 2 * hc + hbit, wo = 2 * wc + wbit;
        #pragma unroll
        for (int r = 0; r < 4; ++r) {
            int m = m0 + wid * 16 + rquad * 4 + r;
            size_t idx = (((size_t)n * M + m) * Ho + ho) * Wo + wo;
            float v = acc[nf][r];
            if (emode == 0)      out[idx] = aux[idx] - v;
            else if (emode == 1) out[idx] = v;
            else                 atomicAdd(&out[idx], v);
        }
    }
}

// ---------------- fp32 implicit-GEMM forward conv (L0, L5) ----------------
template <int KK, int Kk, int S, int P>
__global__ __launch_bounds__(BLK) void conv_gemm(
    const float* __restrict__ Wp, const float* __restrict__ x,
    const float* __restrict__ yin, float* __restrict__ out,
    int M, int Ktot, int Cx, int Hx, int Wx, int Hout, int Wout,
    int kchunk, int emode)
{
    __shared__ float Wt[16][64];
    __shared__ float Xt[16][64];
    int tid = threadIdx.x, tx = tid & 15, ty = tid >> 4;
    int HW = Hout * Wout, HWx = Hx * Wx;
    int pbase = blockIdx.x * 64 + tx * 4;
    int n_[4], ho_[4], wo_[4];
    const float* xb_[4];
    #pragma unroll
    for (int j = 0; j < 4; ++j) {
        int p = pbase + j; int n = p / HW; int r = p - n * HW;
        int ho = r / Wout; int wo = r - ho * Wout;
        n_[j] = n; ho_[j] = ho; wo_[j] = wo;
        xb_[j] = x + (size_t)n * Cx * HWx;
    }
    int m0 = blockIdx.y * 64;
    int kb = blockIdx.z * kchunk, ke = kb + kchunk;
    if (ke > Ktot) ke = Ktot;
    float acc[4][4] = {};
    for (int k0 = kb; k0 < ke; k0 += 16) {
        int kr = k0 + ty;
        *(float4*)&Wt[ty][tx * 4] = *(const float4*)&Wp[(size_t)kr * M + m0 + tx * 4];
        int ci = kr / KK; int t = kr - ci * KK; int kh = t / Kk; int kw = t - kh * Kk;
        int cio = ci * HWx;
        float g[4];
        #pragma unroll
        for (int j = 0; j < 4; ++j) {
            int h = ho_[j] * S - P + kh, w = wo_[j] * S - P + kw;
            g[j] = ((unsigned)h < (unsigned)Hx && (unsigned)w < (unsigned)Wx)
                 ? xb_[j][cio + h * Wx + w] : 0.f;
        }
        *(float4*)&Xt[ty][tx * 4] = make_float4(g[0], g[1], g[2], g[3]);
        __syncthreads();
        #pragma unroll
        for (int kk = 0; kk < 16; ++kk) {
            float4 a = *(float4*)&Wt[kk][ty * 4];
            float4 b = *(float4*)&Xt[kk][tx * 4];
            float aa[4] = {a.x, a.y, a.z, a.w};
            float bb[4] = {b.x, b.y, b.z, b.w};
            #pragma unroll
            for (int i = 0; i < 4; ++i)
                #pragma unroll
                for (int j = 0; j < 4; ++j)
                    acc[i][j] = fmaf(aa[i], bb[j], acc[i][j]);
        }
        __syncthreads();
    }
    #pragma unroll
    for (int i = 0; i < 4; ++i) {
        int m = m0 + ty * 4 + i;
        #pragma unroll
        for (int j = 0; j < 4; ++j) {
            size_t idx = (((size_t)n_[j] * M + m) * Hout + ho_[j]) * Wout + wo_[j];
            float v = acc[i][j];
            if (emode == 0)      out[idx] = fmaxf(MU_F * v - THR_F, 0.f);
            else if (emode == 1) out[idx] = fmaxf(yin[idx] + MU_F * v - THR_F, 0.f);
            else                 atomicAdd(&out[idx], v);
        }
    }
}

// ---------------- 1x1-source transpose conv as plain GEMM (L5) ----------------
__global__ __launch_bounds__(BLK) void outer_gemm(
    const float* __restrict__ Wp, const float* __restrict__ zin,
    const float* __restrict__ aux, float* __restrict__ out,
    int M, int Kz, int emode)
{
    __shared__ float Wt[16][64];
    __shared__ float Xt[16][64];
    int tid = threadIdx.x, tx = tid & 15, ty = tid >> 4;
    int m0 = blockIdx.y * 64;
    float acc[4][4] = {};
    for (int k0 = 0; k0 < Kz; k0 += 16) {
        int kr = k0 + ty;
        *(float4*)&Wt[ty][tx * 4] = *(const float4*)&Wp[(size_t)kr * M + m0 + tx * 4];
        float g[4];
        #pragma unroll
        for (int j = 0; j < 4; ++j) g[j] = zin[(size_t)(tx * 4 + j) * Kz + kr];
        *(float4*)&Xt[ty][tx * 4] = make_float4(g[0], g[1], g[2], g[3]);
        __syncthreads();
        #pragma unroll
        for (int kk = 0; kk < 16; ++kk) {
            float4 a = *(float4*)&Wt[kk][ty * 4];
            float4 b = *(float4*)&Xt[kk][tx * 4];
            float aa[4] = {a.x, a.y, a.z, a.w};
            float bb[4] = {b.x, b.y, b.z, b.w};
            #pragma unroll
            for (int i = 0; i < 4; ++i)
                #pragma unroll
                for (int j = 0; j < 4; ++j)
                    acc[i][j] = fmaf(aa[i], bb[j], acc[i][j]);
        }
        __syncthreads();
    }
    #pragma unroll
    for (int i = 0; i < 4; ++i) {
        int m = m0 + ty * 4 + i;
        #pragma unroll
        for (int j = 0; j < 4; ++j) {
            int n = tx * 4 + j;
            size_t idx = (size_t)n * M + m;
            float v = acc[i][j];
            out[idx] = (emode == 0) ? (aux[idx] - v) : v;
        }
    }
}

// ---------------- M=3 transpose conv (image space, fp32) ----------------
__global__ __launch_bounds__(BLK) void convt_m3(
    const float* __restrict__ Wkc0, const float* __restrict__ z,
    const float* __restrict__ aux, float* __restrict__ out,
    int Cz, int Hz, int Wz, int Ho, int Wo, int emode)
{
    __shared__ float Wl[64 * 4 * 3];
    int tid = threadIdx.x;
    int hbit = blockIdx.z >> 1, wbit = blockIdx.z & 1;
    int khp = 1 - hbit, kwp = 1 - wbit;
    int Ktot = Cz * 4;
    for (int kidx = tid; kidx < Ktot; kidx += BLK) {
        int cz = kidx >> 2, t = kidx & 3, ti = t >> 1, tj = t & 1;
        int tap = (khp + 2 * ti) * 4 + (kwp + 2 * tj);
        Wl[kidx * 3 + 0] = Wkc0[(0 * 16 + tap) * 64 + cz];
        Wl[kidx * 3 + 1] = Wkc0[(1 * 16 + tap) * 64 + cz];
        Wl[kidx * 3 + 2] = Wkc0[(2 * 16 + tap) * 64 + cz];
    }
    __syncthreads();
    int Hc = Ho >> 1, Wc = Wo >> 1, HWc = Hc * Wc;
    int p = blockIdx.x * BLK + tid;
    int n = p / HWc, r = p - n * HWc, hc = r / Wc, wc = r - (r / Wc) * Wc;
    const float* zb = z + (size_t)n * Cz * Hz * Wz;
    int offs[4]; bool val[4];
    #pragma unroll
    for (int t = 0; t < 4; ++t) {
        int ti = t >> 1, tj = t & 1;
        int hn = hc + hbit - ti, wn = wc + wbit - tj;
        val[t] = ((unsigned)hn < (unsigned)Hz) && ((unsigned)wn < (unsigned)Wz);
        offs[t] = hn * Wz + wn;
    }
    float a0 = 0.f, a1 = 0.f, a2 = 0.f;
    int HWz = Hz * Wz;
    for (int cz = 0; cz < Cz; ++cz) {
        const float* base = zb + cz * HWz;
        #pragma unroll
        for (int t = 0; t < 4; ++t) {
            float g = val[t] ? base[offs[t]] : 0.f;
            int wi = (cz * 4 + t) * 3;
            a0 = fmaf(g, Wl[wi + 0], a0);
            a1 = fmaf(g, Wl[wi + 1], a1);
            a2 = fmaf(g, Wl[wi + 2], a2);
        }
    }
    int ho = 2 * hc + hbit, wo = 2 * wc + wbit;
    #pragma unroll
    for (int u = 0; u < 3; ++u) {
        float v = (u == 0) ? a0 : (u == 1) ? a1 : a2;
        size_t idx = (((size_t)n * 3 + u) * Ho + ho) * Wo + wo;
        out[idx] = (emode == 0) ? (aux[idx] - v) : tanhf(v);
    }
}

// ---------------- vectorized epilogues / elementwise (n % 4 == 0) ----------------
__global__ __launch_bounds__(BLK) void shrink_epi_v4(
    const float* __restrict__ p, const float* __restrict__ y,
    float* __restrict__ o, int n4, int mode)
{
    int i = blockIdx.x * BLK + threadIdx.x;
    if (i >= n4) return;
    float4 pv = ((const float4*)p)[i];
    float4 r;
    if (mode == 1) {
        float4 yv = ((const float4*)y)[i];
        r.x = fmaxf(yv.x + MU_F * pv.x - THR_F, 0.f);
        r.y = fmaxf(yv.y + MU_F * pv.y - THR_F, 0.f);
        r.z = fmaxf(yv.z + MU_F * pv.z - THR_F, 0.f);
        r.w = fmaxf(yv.w + MU_F * pv.w - THR_F, 0.f);
    } else {
        r.x = fmaxf(MU_F * pv.x - THR_F, 0.f);
        r.y = fmaxf(MU_F * pv.y - THR_F, 0.f);
        r.z = fmaxf(MU_F * pv.z - THR_F, 0.f);
        r.w = fmaxf(MU_F * pv.w - THR_F, 0.f);
    }
    ((float4*)o)[i] = r;
}

__global__ __launch_bounds__(BLK) void res_epi_v4(
    const float* __restrict__ aux, const float* __restrict__ acc,
    float* __restrict__ o, int n4)
{
    int i = blockIdx.x * BLK + threadIdx.x;
    if (i >= n4) return;
    float4 a = ((const float4*)aux)[i];
    float4 b = ((const float4*)acc)[i];
    ((float4*)o)[i] = make_float4(a.x - b.x, a.y - b.y, a.z - b.z, a.w - b.w);
}

__global__ __launch_bounds__(BLK) void y_update_v4(
    const float* __restrict__ z, const float* __restrict__ zo,
    float* __restrict__ y, int n4, float c)
{
    int i = blockIdx.x * BLK + threadIdx.x;
    if (i >= n4) return;
    float4 zv = ((const float4*)z)[i];
    float4 ov = ((const float4*)zo)[i];
    ((float4*)y)[i] = make_float4(
        fmaf(c, zv.x - ov.x, zv.x), fmaf(c, zv.y - ov.y, zv.y),
        fmaf(c, zv.z - ov.z, zv.z), fmaf(c, zv.w - ov.w, zv.w));
}

// ---------------- two-stage BN stats ----------------
// stage 1: grid (C, nblk) partial reduce -> atomicAdd into stats[c], stats[C+c]
__global__ __launch_bounds__(BLK) void bn_stats_part(
    const float* __restrict__ x, float* __restrict__ stats,
    int N, int C, int HW, int nblk)
{
    int c = blockIdx.x, b = blockIdx.y;
    int cnt = N * HW;
    float s = 0.f, s2 = 0.f;
    for (int i = b * BLK + threadIdx.x; i < cnt; i += nblk * BLK) {
        int n = i / HW, hw = i - n * HW;
        float v = x[((size_t)n * C + c) * HW + hw];
        s += v; s2 = fmaf(v, v, s2);
    }
    float ts  = blk_reduce(s);
    float ts2 = blk_reduce(s2);
    if (threadIdx.x == 0) {
        atomicAdd(&stats[c], ts);
        atomicAdd(&stats[C + c], ts2);
    }
}
// stage 2: finalize mean/rstd
__global__ __launch_bounds__(BLK) void bn_finalize(
    const float* __restrict__ stats, float* __restrict__ mean,
    float* __restrict__ rstd, int C, int cnt)
{
    int c = blockIdx.x * BLK + threadIdx.x;
    if (c >= C) return;
    float m = stats[c] / cnt;
    float var = stats[C + c] / cnt - m * m;
    mean[c] = m;
    rstd[c] = rsqrtf(var + 1e-5f);
}

// ---------------- BN apply + activation, vectorized ----------------
__global__ __launch_bounds__(BLK) void bn_act_v4(
    const float* __restrict__ x, const float* __restrict__ mean,
    const float* __restrict__ rstd, float* __restrict__ out,
    int n4, int C, int HW, int use_bn, int act)
{
    int i = blockIdx.x * BLK + threadIdx.x;
    if (i >= n4) return;
    float4 v = ((const float4*)x)[i];
    float e[4] = {v.x, v.y, v.z, v.w};
    int base = i * 4;
    #pragma unroll
    for (int j = 0; j < 4; ++j) {
        float t = e[j];
        if (use_bn) { int c = ((base + j) / HW) % C; t = (t - mean[c]) * rstd[c]; }
        e[j] = (act == 0) ? ((t >= 0.f) ? t : 0.2f * t) : fmaxf(t, 0.f);
    }
    ((float4*)out)[i] = make_float4(e[0], e[1], e[2], e[3]);
}

// ---------------- per-row L2 normalize ----------------
__global__ __launch_bounds__(128) void rownorm_kernel(
    const float* __restrict__ z, float* __restrict__ out, float* __restrict__ zvec)
{
    __shared__ float sh[128];
    int r = blockIdx.x, tid = threadIdx.x;
    float v = z[r * 128 + tid];
    sh[tid] = v * v;
    __syncthreads();
    #pragma unroll
    for (int s = 64; s > 0; s >>= 1) {
        if (tid < s) sh[tid] += sh[tid + s];
        __syncthreads();
    }
    float nrm = fmaxf(sqrtf(sh[0]), 1e-12f);
    float o = v / nrm;
    out[r * 128 + tid] = o;
    zvec[r * 128 + tid] = o;
}

static inline int gdiv(int a, int b) { return (a + b - 1) / b; }

extern "C" void kernel_launch(void* const* d_in, const int* in_sizes, int n_in,
                              void* d_out, int out_size, void* d_ws, size_t ws_size,
                              hipStream_t stream)
{
    const float* x = (const float*)d_in[0];
    const float* W[6];
    for (int i = 0; i < 6; ++i) W[i] = (const float*)d_in[1 + i];
    float* ws  = (float*)d_ws;
    float* out = (float*)d_out;

    const int Cin[6]  = {3, 64, 128, 256, 512, 1024};
    const int Cout[6] = {64, 128, 256, 512, 1024, 128};
    const int Hin[6]  = {96, 48, 24, 12, 6, 3};
    const int Hout[6] = {48, 24, 12, 6, 3, 1};
    const int N = 64;
    const int SKc[6] = {1, 1, 2, 4, 8, 1};
    const int SKt[6] = {1, 1, 1, 2, 4, 1};

    // ---- workspace layout: ~66.53M floats = 253.8 MB ----
    size_t off = 0;
    float* Wkc0 = ws + off; off += 3072;
    float* Wkc5 = ws + off; off += 1179648;
    float* Wn5  = ws + off; off += 1179648;
    const size_t csz[5] = {0, 131072, 524288, 2097152, 8388608};
    short* Cpk[5]; short* Tpk[5];
    {
        short* sbase = (short*)(ws + off);
        size_t soff = 0;
        for (int L = 1; L < 5; ++L) { Cpk[L] = sbase + soff; soff += 2 * csz[L]; }
        for (int L = 1; L < 5; ++L) { Tpk[L] = sbase + soff; soff += 2 * csz[L]; }
        off += soff / 2;
    }
    const size_t POOL = 30081024;
    float* pool = ws + off; off += POOL;
    float* xb   = ws + off; off += 9437184;
    float* mean = ws + off; off += 1024;
    float* rstd = ws + off; off += 1024;
    float* stats= ws + off; off += 2048;
    float* zvec = ws + off; off += 8192;
    float* pbuf = ws + off; off += 2359296;

    // ---- normalize + pack dictionaries ----
    wnorm_pack<<<64, BLK, 0, stream>>>(W[0], Wkc0, nullptr, 64, 48);
    for (int L = 1; L < 5; ++L)
        wnorm_pack_bf16<<<Cout[L], BLK, 0, stream>>>(W[L], Cpk[L], Tpk[L], Cout[L], Cin[L]);
    wnorm_pack<<<128, BLK, 0, stream>>>(W[5], Wkc5, Wn5, 128, 9216);

    // ---- FISTA momentum coefficients ----
    double td = 1.0; float cc[3];
    for (int i = 0; i < 3; ++i) {
        double tn = (1.0 + sqrt(1.0 + 4.0 * td * td)) * 0.5;
        cc[i] = (float)((td - 1.0) / tn);
        td = tn;
    }

    // two-stage BN helper
    auto run_bn_stats = [&](const float* src, int C, int HW) {
        int cnt = N * HW;
        int nblk = 2048 / C; if (nblk < 1) nblk = 1;
        int maxb = gdiv(cnt, BLK); if (nblk > maxb) nblk = maxb;
        hipMemsetAsync(stats, 0, 2 * C * sizeof(float), stream);
        bn_stats_part<<<dim3(C, nblk), BLK, 0, stream>>>(src, stats, N, C, HW, nblk);
        bn_finalize<<<gdiv(C, BLK), BLK, 0, stream>>>(stats, mean, rstd, C, cnt);
    };

    const float* in = x;
    for (int L = 0; L < 6; ++L) {
        int zTot = N * Cout[L] * Hout[L] * Hout[L];
        int xTot = N * Cin[L] * Hin[L] * Hin[L];
        int npix = N * Hout[L] * Hout[L];
        dim3 ge4(gdiv(zTot / 4, BLK));
        dim3 gr4(gdiv(xTot / 4, BLK));

        float* zA = pool;
        float* zB = pool + (size_t)zTot;
        float* yb = pool + (size_t)2 * zTot;
        float* rb = pool + (size_t)3 * zTot;

        auto launch_conv = [&](const float* src, const float* y, float* dst, int mode) {
            if (L == 5) {
                hipMemsetAsync(pbuf, 0, (size_t)zTot * 4, stream);
                conv_gemm<9, 3, 1, 0><<<dim3(1, 2, 72), BLK, 0, stream>>>(Wkc5, src,
                    nullptr, pbuf, 128, 9216, 1024, 3, 3, 1, 1, 128, 2);
                shrink_epi_v4<<<gdiv(zTot / 4, BLK), BLK, 0, stream>>>(pbuf, y, dst, zTot / 4, mode);
            } else if (L == 0) {
                conv_gemm<16, 4, 2, 1><<<dim3(npix / 64, 1), BLK, 0, stream>>>(
                    Wkc0, src, y, dst, 64, 48, 3, 96, 96, 48, 48, 48, mode);
            } else if (SKc[L] == 1) {
                conv_gemm_bf16<<<dim3(npix / 64, Cout[L] / 64), BLK, 0, stream>>>(
                    Cpk[L], src, y, dst, Cout[L], Cin[L], Hin[L], Hin[L],
                    Hout[L], Hout[L], Cin[L] * 16, mode);
            } else {
                int sk = SKc[L];
                hipMemsetAsync(pbuf, 0, (size_t)zTot * 4, stream);
                conv_gemm_bf16<<<dim3(npix / 64, Cout[L] / 64, sk), BLK, 0, stream>>>(
                    Cpk[L], src, nullptr, pbuf, Cout[L], Cin[L], Hin[L], Hin[L],
                    Hout[L], Hout[L], Cin[L] * 16 / sk, 2);
                shrink_epi_v4<<<gdiv(zTot / 4, BLK), BLK, 0, stream>>>(pbuf, y, dst, zTot / 4, mode);
            }
        };

        // z0 = shrink(MU * conv(in))
        launch_conv(in, nullptr, zA, 0);

        float* z = zA; float* zo = zB;
        for (int it = 0; it < 3; ++it) {
            const float* ybp;
            if (it == 0) {
                ybp = z;                 // c = 0 -> y == z
            } else {
                y_update_v4<<<ge4, BLK, 0, stream>>>(z, zo, yb, zTot / 4, cc[it]);
                ybp = yb;
            }
            // r = in - convT(y)
            if (L == 0) {
                convt_m3<<<dim3(N * 48 * 48 / BLK, 1, 4), BLK, 0, stream>>>(
                    Wkc0, ybp, in, rb, 64, 48, 48, 96, 96, 0);
            } else if (L < 5) {
                int xpixc = N * (Hin[L] / 2) * (Hin[L] / 2);
                int sk = SKt[L];
                if (sk == 1) {
                    convt_gemm_bf16<<<dim3(xpixc / 64, Cin[L] / 64, 4), BLK, 0, stream>>>(
                        Tpk[L], ybp, in, rb, Cin[L], Cout[L], Hout[L], Hout[L],
                        Hin[L], Hin[L], 0, 1);
                } else {
                    hipMemsetAsync(rb, 0, (size_t)xTot * 4, stream);
                    convt_gemm_bf16<<<dim3(xpixc / 64, Cin[L] / 64, 4 * sk), BLK, 0, stream>>>(
                        Tpk[L], ybp, nullptr, rb, Cin[L], Cout[L], Hout[L], Hout[L],
                        Hin[L], Hin[L], 2, sk);
                    res_epi_v4<<<gr4, BLK, 0, stream>>>(in, rb, rb, xTot / 4);
                }
            } else {
                outer_gemm<<<dim3(1, 144), BLK, 0, stream>>>(Wn5, ybp, in, rb, 9216, 128, 0);
            }
            // z_new = shrink(y + MU*conv(r))
            launch_conv(rb, ybp, zo, 1);
            float* tmp = z; z = zo; zo = tmp;
        }

        int HW = Hout[L] * Hout[L];
        if (L == 0) {
            bn_act_v4<<<ge4, BLK, 0, stream>>>(z, nullptr, nullptr, xb, zTot / 4, Cout[L], HW, 0, 0);
            in = xb;
        } else if (L < 5) {
            run_bn_stats(z, Cout[L], HW);
            bn_act_v4<<<ge4, BLK, 0, stream>>>(z, mean, rstd, xb, zTot / 4, Cout[L], HW, 1, 0);
            in = xb;
        } else {
            rownorm_kernel<<<64, 128, 0, stream>>>(z, out, zvec);
        }
    }

    // ---- decoder (bf16x3 convT stages, fp32 elsewhere) ----
    float* zA = pool;
    float* zB = pool + 9437184;
    {
        int oT = N * 1024 * 9;
        outer_gemm<<<dim3(1, 144), BLK, 0, stream>>>(Wn5, zvec, nullptr, zA, 9216, 128, 1);
        run_bn_stats(zA, 1024, 9);
        bn_act_v4<<<gdiv(oT / 4, BLK), BLK, 0, stream>>>(zA, mean, rstd, zB, oT / 4, 1024, 9, 1, 1);
    }
    float* cur = zB;
    for (int i = 4; i >= 1; --i) {
        int oT = N * Cin[i] * Hin[i] * Hin[i];
        int xpixc = N * (Hin[i] / 2) * (Hin[i] / 2);
        int sk = SKt[i];
        if (sk == 1) {
            convt_gemm_bf16<<<dim3(xpixc / 64, Cin[i] / 64, 4), BLK, 0, stream>>>(
                Tpk[i], cur, nullptr, zA, Cin[i], Cout[i], Hout[i], Hout[i],
                Hin[i], Hin[i], 1, 1);
        } else {
            hipMemsetAsync(zA, 0, (size_t)oT * 4, stream);
            convt_gemm_bf16<<<dim3(xpixc / 64, Cin[i] / 64, 4 * sk), BLK, 0, stream>>>(
                Tpk[i], cur, nullptr, zA, Cin[i], Cout[i], Hout[i], Hout[i],
                Hin[i], Hin[i], 2, sk);
        }
        run_bn_stats(zA, Cin[i], Hin[i] * Hin[i]);
        bn_act_v4<<<gdiv(oT / 4, BLK), BLK, 0, stream>>>(zA, mean, rstd, zB, oT / 4,
            Cin[i], Hin[i] * Hin[i], 1, 1);
        cur = zB;
    }
    convt_m3<<<dim3(N * 48 * 48 / BLK, 1, 4), BLK, 0, stream>>>(
        Wkc0, cur, nullptr, out + 8192, 64, 48, 48, 96, 96, 2);
}

// Round 9
// 3787.220 us; speedup vs baseline: 29.6194x; 1.0523x over previous
//
#include <hip/hip_runtime.h>
#include <math.h>

#define BLK 256
static constexpr float MU_F  = 0.1f;
static constexpr float THR_F = 0.01f;

typedef __attribute__((ext_vector_type(8))) short bf16x8;
typedef __attribute__((ext_vector_type(4))) float f32x4;

__device__ inline unsigned short f2bf(float f) {
    unsigned u = __float_as_uint(f);
    unsigned r = (u + 0x7fffu + ((u >> 16) & 1u)) >> 16;   // RNE
    return (unsigned short)r;
}
__device__ inline float bf2f(unsigned short h) {
    return __uint_as_float(((unsigned)h) << 16);
}

// ---------------- block reduction ----------------
__device__ inline float blk_reduce(float v) {
    __shared__ float sh[BLK];
    int tid = threadIdx.x;
    sh[tid] = v;
    __syncthreads();
    #pragma unroll
    for (int s = BLK / 2; s > 0; s >>= 1) {
        if (tid < s) sh[tid] += sh[tid + s];
        __syncthreads();
    }
    float r = sh[0];
    __syncthreads();
    return r;
}

// ---------------- fp32 normalize + pack (L0, L5) ----------------
__global__ __launch_bounds__(BLK) void wnorm_pack(
    const float* __restrict__ W, float* __restrict__ Wkc,
    float* __restrict__ Wnout, int Mout, int asz)
{
    int o = blockIdx.x;
    const float* w = W + (size_t)o * asz;
    float s = 0.f;
    for (int i = threadIdx.x; i < asz; i += BLK) { float v = w[i]; s = fmaf(v, v, s); }
    float tot = blk_reduce(s);
    float inv = 1.0f / (sqrtf(tot) + 1e-12f);
    for (int i = threadIdx.x; i < asz; i += BLK) {
        float v = w[i] * inv;
        Wkc[(size_t)i * Mout + o] = v;
        if (Wnout) Wnout[(size_t)o * asz + i] = v;
    }
}

// ---------------- bf16 hi/lo normalize + MFMA-fragment pack (L1..L4) ----------------
__global__ __launch_bounds__(BLK) void wnorm_pack_bf16(
    const float* __restrict__ W, short* __restrict__ Cpk, short* __restrict__ Tpk,
    int Cout, int Cin)
{
    int o = blockIdx.x;
    int asz = Cin * 16;
    const float* w = W + (size_t)o * asz;
    float s = 0.f;
    for (int i = threadIdx.x; i < asz; i += BLK) { float v = w[i]; s = fmaf(v, v, s); }
    float tot = blk_reduce(s);
    float inv = 1.0f / (sqrtf(tot) + 1e-12f);
    size_t cTot = (size_t)Cout * asz;
    size_t parStride = (size_t)Cout * 4 * Cin;
    size_t tTot = 4 * parStride;
    for (int i = threadIdx.x; i < asz; i += BLK) {
        float v = w[i] * inv;
        unsigned short hb = f2bf(v);
        unsigned short lb = f2bf(v - bf2f(hb));
        size_t cidx = ((size_t)(i >> 3)) * (Cout * 8) + o * 8 + (i & 7);
        Cpk[cidx] = (short)hb;
        Cpk[cTot + cidx] = (short)lb;
        int c = i >> 4, tap = i & 15, kh = tap >> 2, kw = tap & 3;
        int par = (1 - (kh & 1)) * 2 + (1 - (kw & 1));
        int tt = ((kh >> 1) << 1) | (kw >> 1);
        int q = o * 4 + tt;
        size_t tidx = (size_t)par * parStride + ((size_t)(q >> 3)) * (Cin * 8) + c * 8 + (q & 7);
        Tpk[tidx] = (short)hb;
        Tpk[tTot + tidx] = (short)lb;
    }
}

// ---------------- XCD-aware bijective swizzle ----------------
__device__ inline void xcd_remap(int& bx, int& by, int& bz) {
    int nx = gridDim.x, ny = gridDim.y;
    int nwg = nx * ny * gridDim.z;
    int orig = blockIdx.x + nx * (blockIdx.y + ny * blockIdx.z);
    int q8 = nwg >> 3, r8 = nwg & 7, xcd = orig & 7, sidx = orig >> 3;
    int w = (xcd < r8 ? xcd * (q8 + 1) : r8 * (q8 + 1) + (xcd - r8) * q8) + sidx;
    bx = w % nx; int t = w / nx; by = t % ny; bz = t / ny;
}

// ---------------- bf16x3 MFMA implicit-GEMM forward conv (K=4,S=2,P=1) ----------------
__global__ __launch_bounds__(BLK) void conv_gemm_bf16(
    const short* __restrict__ Wpk, const float* __restrict__ x,
    const float* __restrict__ yin, float* __restrict__ out,
    int M, int Cx, int Hx, int Wx, int Hout, int Wout,
    int kchunk, int emode)
{
    __shared__ __align__(16) short Wh[4][64][8];
    __shared__ __align__(16) short Wo_[4][64][8];
    __shared__ __align__(16) short Xh[4][64][8];
    __shared__ __align__(16) short Xo[4][64][8];
    int bx, by, bz; xcd_remap(bx, by, bz);
    int tid = threadIdx.x, lane = tid & 63, wid = tid >> 6;
    int HW = Hout * Wout, HWx = Hx * Wx;
    int pbase = bx * 64, m0 = by * 64, kb = bz * kchunk;
    size_t loOff = (size_t)Cx * 16 * M;

    int spl = tid & 63, skb = tid >> 6;
    int sp = pbase + spl;
    int sn = sp / HW; int srr = sp - sn * HW;
    int sho = srr / Wout, swo = srr - sho * Wout;
    const float* xs = x + (size_t)sn * Cx * HWx;
    int h0 = sho * 2 - 1, w0 = swo * 2 - 1;

    // hoisted gather geometry: tap set fixed per thread, channel advances by 2/iter
    int t16 = (skb & 1) * 8;
    int offs[8]; bool valt[8];
    #pragma unroll
    for (int jj = 0; jj < 8; ++jj) {
        int tap = t16 + jj;
        int kh = tap >> 2, kw = tap & 3;
        int h = h0 + kh, w = w0 + kw;
        valt[jj] = ((unsigned)h < (unsigned)Hx) && ((unsigned)w < (unsigned)Wx);
        offs[jj] = h * Wx + w;
    }
    const float* xc = xs + ((size_t)(kb >> 4) + (skb >> 1)) * HWx;

    f32x4 acc[4] = {};
    for (int k0 = kb; k0 < kb + kchunk; k0 += 32) {
        size_t so = ((size_t)((k0 >> 3) + skb)) * (M * 8) + (size_t)m0 * 8 + spl * 8;
        *(float4*)(&Wh[skb][spl][0])  = *(const float4*)(Wpk + so);
        *(float4*)(&Wo_[skb][spl][0]) = *(const float4*)(Wpk + loOff + so);
        {
            union { short s[8]; float4 f; } uh, ul;
            #pragma unroll
            for (int jj = 0; jj < 8; ++jj) {
                float g = valt[jj] ? xc[offs[jj]] : 0.f;
                unsigned short hb = (unsigned short)(__float_as_uint(g) >> 16);  // trunc
                uh.s[jj] = (short)hb;
                ul.s[jj] = (short)f2bf(g - bf2f(hb));
            }
            *(float4*)(&Xh[skb][spl][0]) = uh.f;
            *(float4*)(&Xo[skb][spl][0]) = ul.f;
        }
        xc += 2 * HWx;
        __syncthreads();
        bf16x8 ah = *(const bf16x8*)(&Wh[lane >> 4][wid * 16 + (lane & 15)][0]);
        bf16x8 al = *(const bf16x8*)(&Wo_[lane >> 4][wid * 16 + (lane & 15)][0]);
        #pragma unroll
        for (int nf = 0; nf < 4; ++nf) {
            bf16x8 bh = *(const bf16x8*)(&Xh[lane >> 4][nf * 16 + (lane & 15)][0]);
            bf16x8 bl = *(const bf16x8*)(&Xo[lane >> 4][nf * 16 + (lane & 15)][0]);
            acc[nf] = __builtin_amdgcn_mfma_f32_16x16x32_bf16(al, bh, acc[nf], 0, 0, 0);
            acc[nf] = __builtin_amdgcn_mfma_f32_16x16x32_bf16(ah, bl, acc[nf], 0, 0, 0);
            acc[nf] = __builtin_amdgcn_mfma_f32_16x16x32_bf16(ah, bh, acc[nf], 0, 0, 0);
        }
        __syncthreads();
    }
    int colp = lane & 15, rquad = lane >> 4;
    #pragma unroll
    for (int nf = 0; nf < 4; ++nf) {
        int p = pbase + nf * 16 + colp;
        int n = p / HW; int rr = p - n * HW;
        int ho = rr / Wout, wo = rr - ho * Wout;
        #pragma unroll
        for (int r = 0; r < 4; ++r) {
            int m = m0 + wid * 16 + rquad * 4 + r;
            size_t idx = (((size_t)n * M + m) * Hout + ho) * Wout + wo;
            float v = acc[nf][r];
            if (emode == 0)      out[idx] = fmaxf(MU_F * v - THR_F, 0.f);
            else if (emode == 1) out[idx] = fmaxf(yin[idx] + MU_F * v - THR_F, 0.f);
            else                 atomicAdd(&out[idx], v);
        }
    }
}

// ---------------- bf16x3 MFMA implicit-GEMM transpose conv ----------------
__global__ __launch_bounds__(BLK) void convt_gemm_bf16(
    const short* __restrict__ Wpk, const float* __restrict__ z,
    const float* __restrict__ aux, float* __restrict__ out,
    int M, int Cz, int Hz, int Wz, int Ho, int Wo, int emode, int SK)
{
    __shared__ __align__(16) short Wh[4][64][8];
    __shared__ __align__(16) short Wo_[4][64][8];
    __shared__ __align__(16) short Xh[4][64][8];
    __shared__ __align__(16) short Xo[4][64][8];
    int bx, by, bz; xcd_remap(bx, by, bz);
    int tid = threadIdx.x, lane = tid & 63, wid = tid >> 6;
    int par = bz / SK, chunk = bz - par * SK;
    int hbit = par >> 1, wbit = par & 1;
    int czs = Cz / SK;
    int qb = chunk * czs * 4;
    size_t parS = (size_t)Cz * 4 * M;
    const short* Wp = Wpk + (size_t)par * parS;
    size_t loOff = 4 * parS;
    int Hc = Ho >> 1, Wc = Wo >> 1, HWc = Hc * Wc;
    int pbase = bx * 64, m0 = by * 64;

    int spl = tid & 63, skb = tid >> 6;
    int sp = pbase + spl;
    int sn = sp / HWc; int srr = sp - sn * HWc;
    int shc = srr / Wc, swc = srr - shc * Wc;
    int HWz = Hz * Wz;
    const float* zs = z + (size_t)sn * Cz * HWz;

    // hoisted gather geometry: 4 taps fixed per thread, channel advances by 8/iter
    int offt[4]; bool valt[4];
    #pragma unroll
    for (int t = 0; t < 4; ++t) {
        int ti = t >> 1, tj = t & 1;
        int hn = shc + hbit - ti, wn = swc + wbit - tj;
        valt[t] = ((unsigned)hn < (unsigned)Hz) && ((unsigned)wn < (unsigned)Wz);
        offt[t] = hn * Wz + wn;
    }
    const float* zc = zs + ((size_t)(qb >> 2) + skb * 2) * HWz;

    f32x4 acc[4] = {};
    for (int q0 = qb; q0 < qb + czs * 4; q0 += 32) {
        size_t so = ((size_t)((q0 >> 3) + skb)) * (M * 8) + (size_t)m0 * 8 + spl * 8;
        *(float4*)(&Wh[skb][spl][0])  = *(const float4*)(Wp + so);
        *(float4*)(&Wo_[skb][spl][0]) = *(const float4*)(Wp + loOff + so);
        {
            union { short s[8]; float4 f; } uh, ul;
            #pragma unroll
            for (int jj = 0; jj < 8; ++jj) {
                int t = jj & 3;
                float g = valt[t] ? zc[(jj >> 2) * HWz + offt[t]] : 0.f;
                unsigned short hb = (unsigned short)(__float_as_uint(g) >> 16);  // trunc
                uh.s[jj] = (short)hb;
                ul.s[jj] = (short)f2bf(g - bf2f(hb));
            }
            *(float4*)(&Xh[skb][spl][0]) = uh.f;
            *(float4*)(&Xo[skb][spl][0]) = ul.f;
        }
        zc += 8 * HWz;
        __syncthreads();
        bf16x8 ah = *(const bf16x8*)(&Wh[lane >> 4][wid * 16 + (lane & 15)][0]);
        bf16x8 al = *(const bf16x8*)(&Wo_[lane >> 4][wid * 16 + (lane & 15)][0]);
        #pragma unroll
        for (int nf = 0; nf < 4; ++nf) {
            bf16x8 bh = *(const bf16x8*)(&Xh[lane >> 4][nf * 16 + (lane & 15)][0]);
            bf16x8 bl = *(const bf16x8*)(&Xo[lane >> 4][nf * 16 + (lane & 15)][0]);
            acc[nf] = __builtin_amdgcn_mfma_f32_16x16x32_bf16(al, bh, acc[nf], 0, 0, 0);
            acc[nf] = __builtin_amdgcn_mfma_f32_16x16x32_bf16(ah, bl, acc[nf], 0, 0, 0);
            acc[nf] = __builtin_amdgcn_mfma_f32_16x16x32_bf16(ah, bh, acc[nf], 0, 0, 0);
        }
        __syncthreads();
    }
    int colp = lane & 15, rquad = lane >> 4;
    #pragma unroll
    for (int nf = 0; nf < 4; ++nf) {
        int p = pbase + nf * 16 + colp;
        int n = p / HWc; int rr = p - n * HWc;
        int hc = rr / Wc, wc = rr - hc * Wc;
        int ho = 2 * hc + hbit, wo = 2 * wc + wbit;
        #pragma unroll
        for (int r = 0; r < 4; ++r) {
            int m = m0 + wid * 16 + rquad * 4 + r;
            size_t idx = (((size_t)n * M + m) * Ho + ho) * Wo + wo;
            float v = acc[nf][r];
            if (emode == 0)      out[idx] = aux[idx] - v;
            else if (emode == 1) out[idx] = v;
            else                 atomicAdd(&out[idx], v);
        }
    }
}

// ---------------- fp32 implicit-GEMM forward conv (L0, L5) ----------------
template <int KK, int Kk, int S, int P>
__global__ __launch_bounds__(BLK) void conv_gemm(
    const float* __restrict__ Wp, const float* __restrict__ x,
    const float* __restrict__ yin, float* __restrict__ out,
    int M, int Ktot, int Cx, int Hx, int Wx, int Hout, int Wout,
    int kchunk, int emode)
{
    __shared__ float Wt[16][64];
    __shared__ float Xt[16][64];
    int tid = threadIdx.x, tx = tid & 15, ty = tid >> 4;
    int HW = Hout * Wout, HWx = Hx * Wx;
    int pbase = blockIdx.x * 64 + tx * 4;
    int n_[4], ho_[4], wo_[4];
    const float* xb_[4];
    #pragma unroll
    for (int j = 0; j < 4; ++j) {
        int p = pbase + j; int n = p / HW; int r = p - n * HW;
        int ho = r / Wout; int wo = r - ho * Wout;
        n_[j] = n; ho_[j] = ho; wo_[j] = wo;
        xb_[j] = x + (size_t)n * Cx * HWx;
    }
    int m0 = blockIdx.y * 64;
    int kb = blockIdx.z * kchunk, ke = kb + kchunk;
    if (ke > Ktot) ke = Ktot;
    float acc[4][4] = {};
    for (int k0 = kb; k0 < ke; k0 += 16) {
        int kr = k0 + ty;
        *(float4*)&Wt[ty][tx * 4] = *(const float4*)&Wp[(size_t)kr * M + m0 + tx * 4];
        int ci = kr / KK; int t = kr - ci * KK; int kh = t / Kk; int kw = t - kh * Kk;
        int cio = ci * HWx;
        float g[4];
        #pragma unroll
        for (int j = 0; j < 4; ++j) {
            int h = ho_[j] * S - P + kh, w = wo_[j] * S - P + kw;
            g[j] = ((unsigned)h < (unsigned)Hx && (unsigned)w < (unsigned)Wx)
                 ? xb_[j][cio + h * Wx + w] : 0.f;
        }
        *(float4*)&Xt[ty][tx * 4] = make_float4(g[0], g[1], g[2], g[3]);
        __syncthreads();
        #pragma unroll
        for (int kk = 0; kk < 16; ++kk) {
            float4 a = *(float4*)&Wt[kk][ty * 4];
            float4 b = *(float4*)&Xt[kk][tx * 4];
            float aa[4] = {a.x, a.y, a.z, a.w};
            float bb[4] = {b.x, b.y, b.z, b.w};
            #pragma unroll
            for (int i = 0; i < 4; ++i)
                #pragma unroll
                for (int j = 0; j < 4; ++j)
                    acc[i][j] = fmaf(aa[i], bb[j], acc[i][j]);
        }
        __syncthreads();
    }
    #pragma unroll
    for (int i = 0; i < 4; ++i) {
        int m = m0 + ty * 4 + i;
        #pragma unroll
        for (int j = 0; j < 4; ++j) {
            size_t idx = (((size_t)n_[j] * M + m) * Hout + ho_[j]) * Wout + wo_[j];
            float v = acc[i][j];
            if (emode == 0)      out[idx] = fmaxf(MU_F * v - THR_F, 0.f);
            else if (emode == 1) out[idx] = fmaxf(yin[idx] + MU_F * v - THR_F, 0.f);
            else                 atomicAdd(&out[idx], v);
        }
    }
}

// ---------------- 1x1-source transpose conv as plain GEMM (L5) ----------------
__global__ __launch_bounds__(BLK) void outer_gemm(
    const float* __restrict__ Wp, const float* __restrict__ zin,
    const float* __restrict__ aux, float* __restrict__ out,
    int M, int Kz, int emode)
{
    __shared__ float Wt[16][64];
    __shared__ float Xt[16][64];
    int tid = threadIdx.x, tx = tid & 15, ty = tid >> 4;
    int m0 = blockIdx.y * 64;
    float acc[4][4] = {};
    for (int k0 = 0; k0 < Kz; k0 += 16) {
        int kr = k0 + ty;
        *(float4*)&Wt[ty][tx * 4] = *(const float4*)&Wp[(size_t)kr * M + m0 + tx * 4];
        float g[4];
        #pragma unroll
        for (int j = 0; j < 4; ++j) g[j] = zin[(size_t)(tx * 4 + j) * Kz + kr];
        *(float4*)&Xt[ty][tx * 4] = make_float4(g[0], g[1], g[2], g[3]);
        __syncthreads();
        #pragma unroll
        for (int kk = 0; kk < 16; ++kk) {
            float4 a = *(float4*)&Wt[kk][ty * 4];
            float4 b = *(float4*)&Xt[kk][tx * 4];
            float aa[4] = {a.x, a.y, a.z, a.w};
            float bb[4] = {b.x, b.y, b.z, b.w};
            #pragma unroll
            for (int i = 0; i < 4; ++i)
                #pragma unroll
                for (int j = 0; j < 4; ++j)
                    acc[i][j] = fmaf(aa[i], bb[j], acc[i][j]);
        }
        __syncthreads();
    }
    #pragma unroll
    for (int i = 0; i < 4; ++i) {
        int m = m0 + ty * 4 + i;
        #pragma unroll
        for (int j = 0; j < 4; ++j) {
            int n = tx * 4 + j;
            size_t idx = (size_t)n * M + m;
            float v = acc[i][j];
            out[idx] = (emode == 0) ? (aux[idx] - v) : v;
        }
    }
}

// ---------------- M=3 transpose conv (image space, fp32) ----------------
__global__ __launch_bounds__(BLK) void convt_m3(
    const float* __restrict__ Wkc0, const float* __restrict__ z,
    const float* __restrict__ aux, float* __restrict__ out,
    int Cz, int Hz, int Wz, int Ho, int Wo, int emode)
{
    __shared__ float Wl[64 * 4 * 3];
    int tid = threadIdx.x;
    int hbit = blockIdx.z >> 1, wbit = blockIdx.z & 1;
    int khp = 1 - hbit, kwp = 1 - wbit;
    int Ktot = Cz * 4;
    for (int kidx = tid; kidx < Ktot; kidx += BLK) {
        int cz = kidx >> 2, t = kidx & 3, ti = t >> 1, tj = t & 1;
        int tap = (khp + 2 * ti) * 4 + (kwp + 2 * tj);
        Wl[kidx * 3 + 0] = Wkc0[(0 * 16 + tap) * 64 + cz];
        Wl[kidx * 3 + 1] = Wkc0[(1 * 16 + tap) * 64 + cz];
        Wl[kidx * 3 + 2] = Wkc0[(2 * 16 + tap) * 64 + cz];
    }
    __syncthreads();
    int Hc = Ho >> 1, Wc = Wo >> 1, HWc = Hc * Wc;
    int p = blockIdx.x * BLK + tid;
    int n = p / HWc, r = p - n * HWc, hc = r / Wc, wc = r - (r / Wc) * Wc;
    const float* zb = z + (size_t)n * Cz * Hz * Wz;
    int offs[4]; bool val[4];
    #pragma unroll
    for (int t = 0; t < 4; ++t) {
        int ti = t >> 1, tj = t & 1;
        int hn = hc + hbit - ti, wn = wc + wbit - tj;
        val[t] = ((unsigned)hn < (unsigned)Hz) && ((unsigned)wn < (unsigned)Wz);
        offs[t] = hn * Wz + wn;
    }
    float a0 = 0.f, a1 = 0.f, a2 = 0.f;
    int HWz = Hz * Wz;
    for (int cz = 0; cz < Cz; ++cz) {
        const float* base = zb + cz * HWz;
        #pragma unroll
        for (int t = 0; t < 4; ++t) {
            float g = val[t] ? base[offs[t]] : 0.f;
            int wi = (cz * 4 + t) * 3;
            a0 = fmaf(g, Wl[wi + 0], a0);
            a1 = fmaf(g, Wl[wi + 1], a1);
            a2 = fmaf(g, Wl[wi + 2], a2);
        }
    }
    int ho = 2 * hc + hbit, wo = 2 * wc + wbit;
    #pragma unroll
    for (int u = 0; u < 3; ++u) {
        float v = (u == 0) ? a0 : (u == 1) ? a1 : a2;
        size_t idx = (((size_t)n * 3 + u) * Ho + ho) * Wo + wo;
        out[idx] = (emode == 0) ? (aux[idx] - v) : tanhf(v);
    }
}

// ---------------- vectorized epilogues / elementwise (n % 4 == 0) ----------------
__global__ __launch_bounds__(BLK) void shrink_epi_v4(
    const float* __restrict__ p, const float* __restrict__ y,
    float* __restrict__ o, int n4, int mode)
{
    int i = blockIdx.x * BLK + threadIdx.x;
    if (i >= n4) return;
    float4 pv = ((const float4*)p)[i];
    float4 r;
    if (mode == 1) {
        float4 yv = ((const float4*)y)[i];
        r.x = fmaxf(yv.x + MU_F * pv.x - THR_F, 0.f);
        r.y = fmaxf(yv.y + MU_F * pv.y - THR_F, 0.f);
        r.z = fmaxf(yv.z + MU_F * pv.z - THR_F, 0.f);
        r.w = fmaxf(yv.w + MU_F * pv.w - THR_F, 0.f);
    } else {
        r.x = fmaxf(MU_F * pv.x - THR_F, 0.f);
        r.y = fmaxf(MU_F * pv.y - THR_F, 0.f);
        r.z = fmaxf(MU_F * pv.z - THR_F, 0.f);
        r.w = fmaxf(MU_F * pv.w - THR_F, 0.f);
    }
    ((float4*)o)[i] = r;
}

__global__ __launch_bounds__(BLK) void res_epi_v4(
    const float* __restrict__ aux, const float* __restrict__ acc,
    float* __restrict__ o, int n4)
{
    int i = blockIdx.x * BLK + threadIdx.x;
    if (i >= n4) return;
    float4 a = ((const float4*)aux)[i];
    float4 b = ((const float4*)acc)[i];
    ((float4*)o)[i] = make_float4(a.x - b.x, a.y - b.y, a.z - b.z, a.w - b.w);
}

__global__ __launch_bounds__(BLK) void y_update_v4(
    const float* __restrict__ z, const float* __restrict__ zo,
    float* __restrict__ y, int n4, float c)
{
    int i = blockIdx.x * BLK + threadIdx.x;
    if (i >= n4) return;
    float4 zv = ((const float4*)z)[i];
    float4 ov = ((const float4*)zo)[i];
    ((float4*)y)[i] = make_float4(
        fmaf(c, zv.x - ov.x, zv.x), fmaf(c, zv.y - ov.y, zv.y),
        fmaf(c, zv.z - ov.z, zv.z), fmaf(c, zv.w - ov.w, zv.w));
}

// ---------------- two-stage BN stats ----------------
__global__ __launch_bounds__(BLK) void bn_stats_part(
    const float* __restrict__ x, float* __restrict__ stats,
    int N, int C, int HW, int nblk)
{
    int c = blockIdx.x, b = blockIdx.y;
    int cnt = N * HW;
    float s = 0.f, s2 = 0.f;
    for (int i = b * BLK + threadIdx.x; i < cnt; i += nblk * BLK) {
        int n = i / HW, hw = i - n * HW;
        float v = x[((size_t)n * C + c) * HW + hw];
        s += v; s2 = fmaf(v, v, s2);
    }
    float ts  = blk_reduce(s);
    float ts2 = blk_reduce(s2);
    if (threadIdx.x == 0) {
        atomicAdd(&stats[c], ts);
        atomicAdd(&stats[C + c], ts2);
    }
}
__global__ __launch_bounds__(BLK) void bn_finalize(
    const float* __restrict__ stats, float* __restrict__ mean,
    float* __restrict__ rstd, int C, int cnt)
{
    int c = blockIdx.x * BLK + threadIdx.x;
    if (c >= C) return;
    float m = stats[c] / cnt;
    float var = stats[C + c] / cnt - m * m;
    mean[c] = m;
    rstd[c] = rsqrtf(var + 1e-5f);
}

// ---------------- BN apply + activation, vectorized ----------------
__global__ __launch_bounds__(BLK) void bn_act_v4(
    const float* __restrict__ x, const float* __restrict__ mean,
    const float* __restrict__ rstd, float* __restrict__ out,
    int n4, int C, int HW, int use_bn, int act)
{
    int i = blockIdx.x * BLK + threadIdx.x;
    if (i >= n4) return;
    float4 v = ((const float4*)x)[i];
    float e[4] = {v.x, v.y, v.z, v.w};
    int base = i * 4;
    #pragma unroll
    for (int j = 0; j < 4; ++j) {
        float t = e[j];
        if (use_bn) { int c = ((base + j) / HW) % C; t = (t - mean[c]) * rstd[c]; }
        e[j] = (act == 0) ? ((t >= 0.f) ? t : 0.2f * t) : fmaxf(t, 0.f);
    }
    ((float4*)out)[i] = make_float4(e[0], e[1], e[2], e[3]);
}

// ---------------- per-row L2 normalize ----------------
__global__ __launch_bounds__(128) void rownorm_kernel(
    const float* __restrict__ z, float* __restrict__ out, float* __restrict__ zvec)
{
    __shared__ float sh[128];
    int r = blockIdx.x, tid = threadIdx.x;
    float v = z[r * 128 + tid];
    sh[tid] = v * v;
    __syncthreads();
    #pragma unroll
    for (int s = 64; s > 0; s >>= 1) {
        if (tid < s) sh[tid] += sh[tid + s];
        __syncthreads();
    }
    float nrm = fmaxf(sqrtf(sh[0]), 1e-12f);
    float o = v / nrm;
    out[r * 128 + tid] = o;
    zvec[r * 128 + tid] = o;
}

static inline int gdiv(int a, int b) { return (a + b - 1) / b; }

extern "C" void kernel_launch(void* const* d_in, const int* in_sizes, int n_in,
                              void* d_out, int out_size, void* d_ws, size_t ws_size,
                              hipStream_t stream)
{
    const float* x = (const float*)d_in[0];
    const float* W[6];
    for (int i = 0; i < 6; ++i) W[i] = (const float*)d_in[1 + i];
    float* ws  = (float*)d_ws;
    float* out = (float*)d_out;

    const int Cin[6]  = {3, 64, 128, 256, 512, 1024};
    const int Cout[6] = {64, 128, 256, 512, 1024, 128};
    const int Hin[6]  = {96, 48, 24, 12, 6, 3};
    const int Hout[6] = {48, 24, 12, 6, 3, 1};
    const int N = 64;
    const int SKc[6] = {1, 1, 2, 4, 8, 1};
    const int SKt[6] = {1, 1, 1, 2, 4, 1};

    // ---- workspace layout: ~66.53M floats = 253.8 MB ----
    size_t off = 0;
    float* Wkc0 = ws + off; off += 3072;
    float* Wkc5 = ws + off; off += 1179648;
    float* Wn5  = ws + off; off += 1179648;
    const size_t csz[5] = {0, 131072, 524288, 2097152, 8388608};
    short* Cpk[5]; short* Tpk[5];
    {
        short* sbase = (short*)(ws + off);
        size_t soff = 0;
        for (int L = 1; L < 5; ++L) { Cpk[L] = sbase + soff; soff += 2 * csz[L]; }
        for (int L = 1; L < 5; ++L) { Tpk[L] = sbase + soff; soff += 2 * csz[L]; }
        off += soff / 2;
    }
    const size_t POOL = 30081024;
    float* pool = ws + off; off += POOL;
    float* xb   = ws + off; off += 9437184;
    float* mean = ws + off; off += 1024;
    float* rstd = ws + off; off += 1024;
    float* stats= ws + off; off += 2048;
    float* zvec = ws + off; off += 8192;
    float* pbuf = ws + off; off += 2359296;

    // ---- normalize + pack dictionaries ----
    wnorm_pack<<<64, BLK, 0, stream>>>(W[0], Wkc0, nullptr, 64, 48);
    for (int L = 1; L < 5; ++L)
        wnorm_pack_bf16<<<Cout[L], BLK, 0, stream>>>(W[L], Cpk[L], Tpk[L], Cout[L], Cin[L]);
    wnorm_pack<<<128, BLK, 0, stream>>>(W[5], Wkc5, Wn5, 128, 9216);

    // ---- FISTA momentum coefficients ----
    double td = 1.0; float cc[3];
    for (int i = 0; i < 3; ++i) {
        double tn = (1.0 + sqrt(1.0 + 4.0 * td * td)) * 0.5;
        cc[i] = (float)((td - 1.0) / tn);
        td = tn;
    }

    auto run_bn_stats = [&](const float* src, int C, int HW) {
        int cnt = N * HW;
        int nblk = 2048 / C; if (nblk < 1) nblk = 1;
        int maxb = gdiv(cnt, BLK); if (nblk > maxb) nblk = maxb;
        hipMemsetAsync(stats, 0, 2 * C * sizeof(float), stream);
        bn_stats_part<<<dim3(C, nblk), BLK, 0, stream>>>(src, stats, N, C, HW, nblk);
        bn_finalize<<<gdiv(C, BLK), BLK, 0, stream>>>(stats, mean, rstd, C, cnt);
    };

    const float* in = x;
    for (int L = 0; L < 6; ++L) {
        int zTot = N * Cout[L] * Hout[L] * Hout[L];
        int xTot = N * Cin[L] * Hin[L] * Hin[L];
        int npix = N * Hout[L] * Hout[L];
        dim3 ge4(gdiv(zTot / 4, BLK));
        dim3 gr4(gdiv(xTot / 4, BLK));

        float* zA = pool;
        float* zB = pool + (size_t)zTot;
        float* yb = pool + (size_t)2 * zTot;
        float* rb = pool + (size_t)3 * zTot;

        auto launch_conv = [&](const float* src, const float* y, float* dst, int mode) {
            if (L == 5) {
                hipMemsetAsync(pbuf, 0, (size_t)zTot * 4, stream);
                conv_gemm<9, 3, 1, 0><<<dim3(1, 2, 72), BLK, 0, stream>>>(Wkc5, src,
                    nullptr, pbuf, 128, 9216, 1024, 3, 3, 1, 1, 128, 2);
                shrink_epi_v4<<<gdiv(zTot / 4, BLK), BLK, 0, stream>>>(pbuf, y, dst, zTot / 4, mode);
            } else if (L == 0) {
                conv_gemm<16, 4, 2, 1><<<dim3(npix / 64, 1), BLK, 0, stream>>>(
                    Wkc0, src, y, dst, 64, 48, 3, 96, 96, 48, 48, 48, mode);
            } else if (SKc[L] == 1) {
                conv_gemm_bf16<<<dim3(npix / 64, Cout[L] / 64), BLK, 0, stream>>>(
                    Cpk[L], src, y, dst, Cout[L], Cin[L], Hin[L], Hin[L],
                    Hout[L], Hout[L], Cin[L] * 16, mode);
            } else {
                int sk = SKc[L];
                hipMemsetAsync(pbuf, 0, (size_t)zTot * 4, stream);
                conv_gemm_bf16<<<dim3(npix / 64, Cout[L] / 64, sk), BLK, 0, stream>>>(
                    Cpk[L], src, nullptr, pbuf, Cout[L], Cin[L], Hin[L], Hin[L],
                    Hout[L], Hout[L], Cin[L] * 16 / sk, 2);
                shrink_epi_v4<<<gdiv(zTot / 4, BLK), BLK, 0, stream>>>(pbuf, y, dst, zTot / 4, mode);
            }
        };

        // z0 = shrink(MU * conv(in))
        launch_conv(in, nullptr, zA, 0);

        float* z = zA; float* zo = zB;
        for (int it = 0; it < 3; ++it) {
            const float* ybp;
            if (it == 0) {
                ybp = z;                 // c = 0 -> y == z
            } else {
                y_update_v4<<<ge4, BLK, 0, stream>>>(z, zo, yb, zTot / 4, cc[it]);
                ybp = yb;
            }
            // r = in - convT(y)
            if (L == 0) {
                convt_m3<<<dim3(N * 48 * 48 / BLK, 1, 4), BLK, 0, stream>>>(
                    Wkc0, ybp, in, rb, 64, 48, 48, 96, 96, 0);
            } else if (L < 5) {
                int xpixc = N * (Hin[L] / 2) * (Hin[L] / 2);
                int sk = SKt[L];
                if (sk == 1) {
                    convt_gemm_bf16<<<dim3(xpixc / 64, Cin[L] / 64, 4), BLK, 0, stream>>>(
                        Tpk[L], ybp, in, rb, Cin[L], Cout[L], Hout[L], Hout[L],
                        Hin[L], Hin[L], 0, 1);
                } else {
                    hipMemsetAsync(rb, 0, (size_t)xTot * 4, stream);
                    convt_gemm_bf16<<<dim3(xpixc / 64, Cin[L] / 64, 4 * sk), BLK, 0, stream>>>(
                        Tpk[L], ybp, nullptr, rb, Cin[L], Cout[L], Hout[L], Hout[L],
                        Hin[L], Hin[L], 2, sk);
                    res_epi_v4<<<gr4, BLK, 0, stream>>>(in, rb, rb, xTot / 4);
                }
            } else {
                outer_gemm<<<dim3(1, 144), BLK, 0, stream>>>(Wn5, ybp, in, rb, 9216, 128, 0);
            }
            // z_new = shrink(y + MU*conv(r))
            launch_conv(rb, ybp, zo, 1);
            float* tmp = z; z = zo; zo = tmp;
        }

        int HW = Hout[L] * Hout[L];
        if (L == 0) {
            bn_act_v4<<<ge4, BLK, 0, stream>>>(z, nullptr, nullptr, xb, zTot / 4, Cout[L], HW, 0, 0);
            in = xb;
        } else if (L < 5) {
            run_bn_stats(z, Cout[L], HW);
            bn_act_v4<<<ge4, BLK, 0, stream>>>(z, mean, rstd, xb, zTot / 4, Cout[L], HW, 1, 0);
            in = xb;
        } else {
            rownorm_kernel<<<64, 128, 0, stream>>>(z, out, zvec);
        }
    }

    // ---- decoder (bf16x3 convT stages, fp32 elsewhere) ----
    float* zA = pool;
    float* zB = pool + 9437184;
    {
        int oT = N * 1024 * 9;
        outer_gemm<<<dim3(1, 144), BLK, 0, stream>>>(Wn5, zvec, nullptr, zA, 9216, 128, 1);
        run_bn_stats(zA, 1024, 9);
        bn_act_v4<<<gdiv(oT / 4, BLK), BLK, 0, stream>>>(zA, mean, rstd, zB, oT / 4, 1024, 9, 1, 1);
    }
    float* cur = zB;
    for (int i = 4; i >= 1; --i) {
        int oT = N * Cin[i] * Hin[i] * Hin[i];
        int xpixc = N * (Hin[i] / 2) * (Hin[i] / 2);
        int sk = SKt[i];
        if (sk == 1) {
            convt_gemm_bf16<<<dim3(xpixc / 64, Cin[i] / 64, 4), BLK, 0, stream>>>(
                Tpk[i], cur, nullptr, zA, Cin[i], Cout[i], Hout[i], Hout[i],
                Hin[i], Hin[i], 1, 1);
        } else {
            hipMemsetAsync(zA, 0, (size_t)oT * 4, stream);
            convt_gemm_bf16<<<dim3(xpixc / 64, Cin[i] / 64, 4 * sk), BLK, 0, stream>>>(
                Tpk[i], cur, nullptr, zA, Cin[i], Cout[i], Hout[i], Hout[i],
                Hin[i], Hin[i], 2, sk);
        }
        run_bn_stats(zA, Cin[i], Hin[i] * Hin[i]);
        bn_act_v4<<<gdiv(oT / 4, BLK), BLK, 0, stream>>>(zA, mean, rstd, zB, oT / 4,
            Cin[i], Hin[i] * Hin[i], 1, 1);
        cur = zB;
    }
    convt_m3<<<dim3(N * 48 * 48 / BLK, 1, 4), BLK, 0, stream>>>(
        Wkc0, cur, nullptr, out + 8192, 64, 48, 48, 96, 96, 2);
}